// Round 2
// baseline (1329.002 us; speedup 1.0000x reference)
//
#include <hip/hip_runtime.h>
#include <hip/hip_bf16.h>

#define NN   20000
#define NE   320000
#define HID  256
#define EDIM 128
#define DDIM 64
#define TDIM 256
#define INCH 704

typedef __attribute__((ext_vector_type(8))) short bf16x8;
typedef __attribute__((ext_vector_type(4))) float f32x4;
typedef __attribute__((ext_vector_type(4))) unsigned int u32x4;

__device__ __forceinline__ unsigned short f2bu(float x) {
    return __bfloat16_as_ushort(__float2bfloat16(x));
}
__device__ __forceinline__ unsigned pk2(float lo, float hi) {
    return (unsigned)f2bu(lo) | ((unsigned)f2bu(hi) << 16);
}
__device__ __forceinline__ float ulo(unsigned u) {
    return __bfloat162float(__ushort_as_bfloat16((unsigned short)(u & 0xffffu)));
}
__device__ __forceinline__ float uhi(unsigned u) {
    return __bfloat162float(__ushort_as_bfloat16((unsigned short)(u >> 16)));
}
__device__ __forceinline__ float silu_f(float x) {
    return x / (1.0f + __expf(-x));
}

// Pack fp32 [K][Nc] row-major weight into bf16 MFMA B-fragment order:
// frag element j of lane l of tile (kt,nt) = B[kt*32 + (l>>4)*8 + j][nt*16 + (l&15)]
// stored at dst[((kt*NT+nt)*64 + l)*8 + j]. A staging uses the same (l>>4, j)->k
// mapping, so any HW within-K-tile permutation cancels.
__global__ void pack_weights(const float* __restrict__ src, unsigned short* __restrict__ dst,
                             int K, int Nc) {
    int KT = K >> 5, NT = Nc >> 4;
    int total = KT * NT * 64;
    int idx = blockIdx.x * blockDim.x + threadIdx.x;
    if (idx >= total) return;
    int lane = idx & 63;
    int tile = idx >> 6;
    int nt = tile % NT, kt = tile / NT;
    int n = nt * 16 + (lane & 15);
    int k0 = kt * 32 + (lane >> 4) * 8;
    alignas(16) unsigned short v[8];
#pragma unroll
    for (int j = 0; j < 8; ++j) v[j] = f2bu(src[(size_t)(k0 + j) * Nc + n]);
    *reinterpret_cast<u32x4*>(dst + (size_t)idx * 8) = *reinterpret_cast<const u32x4*>(v);
}

__global__ void init_out(const float* __restrict__ pos, float* __restrict__ out, int n) {
    int i = blockIdx.x * blockDim.x + threadIdx.x;
    if (i < n) out[i] = pos[i];
}

__global__ __launch_bounds__(256, 3) void edge_kernel(
    const float* __restrict__ h, const float* __restrict__ pos,
    const float* __restrict__ edge_attr, const float* __restrict__ dist,
    const float* __restrict__ time_emb, const int* __restrict__ edge_index,
    const float* __restrict__ b_time, const float* __restrict__ b_in,
    const float* __restrict__ b_c1, const float* __restrict__ W_c2,
    const float* __restrict__ coord_scale,
    const unsigned short* __restrict__ pWtime, const unsigned short* __restrict__ pWin,
    const unsigned short* __restrict__ pWc1,
    float* __restrict__ out)
{
    // One 33792-byte region, time-multiplexed (barriers separate the three uses):
    //   sT [64][264] bf16 : silu(time_emb) staged once     (phase T)
    //   sX [2][64][72]    : double-buffered BK=64 A-chunks (phase Y)
    //   sU [64][264]      : FiLM'd LN output               (phase Z)
    __shared__ __align__(16) unsigned char smem[64 * 264 * 2];
    __hip_bfloat16 (*sT)[264]    = reinterpret_cast<__hip_bfloat16(*)[264]>(smem);
    __hip_bfloat16 (*sU)[264]    = reinterpret_cast<__hip_bfloat16(*)[264]>(smem);
    __hip_bfloat16 (*sX)[64][72] = reinterpret_cast<__hip_bfloat16(*)[64][72]>(smem);
    __shared__ float sSum[64], sSq[64], sS[64];
    __shared__ int sRow[64], sCol[64];

    const int tid = threadIdx.x;
    const int wave = tid >> 6, lane = tid & 63;
    const int lq = lane >> 4, lr = lane & 15;
    const int e0 = blockIdx.x * 64;
    const int el = tid >> 2, part = tid & 3;

    if (tid < 64) {
        sRow[tid] = edge_index[e0 + tid];
        sCol[tid] = edge_index[NE + e0 + tid];
        sSum[tid] = 0.f; sSq[tid] = 0.f; sS[tid] = 0.f;
    }

    // ---- stage silu(time_emb) block into sT (bf16), once ----
    {
        const float* p = time_emb + (size_t)(e0 + el) * TDIM + part * 64;
#pragma unroll
        for (int j = 0; j < 4; ++j) {
            float4 a = *reinterpret_cast<const float4*>(p + j * 16);
            float4 b = *reinterpret_cast<const float4*>(p + j * 16 + 4);
            float4 c = *reinterpret_cast<const float4*>(p + j * 16 + 8);
            float4 d = *reinterpret_cast<const float4*>(p + j * 16 + 12);
            u32x4 w0, w1;
            w0.x = pk2(silu_f(a.x), silu_f(a.y)); w0.y = pk2(silu_f(a.z), silu_f(a.w));
            w0.z = pk2(silu_f(b.x), silu_f(b.y)); w0.w = pk2(silu_f(b.z), silu_f(b.w));
            w1.x = pk2(silu_f(c.x), silu_f(c.y)); w1.y = pk2(silu_f(c.z), silu_f(c.w));
            w1.z = pk2(silu_f(d.x), silu_f(d.y)); w1.w = pk2(silu_f(d.z), silu_f(d.w));
            *reinterpret_cast<u32x4*>(&sT[el][part * 64 + j * 16]) = w0;
            *reinterpret_cast<u32x4*>(&sT[el][part * 64 + j * 16 + 8]) = w1;
        }
    }
    __syncthreads();   // B1: sT + sRow/sCol ready

    const int rIdx = sRow[el], cIdx = sCol[el];

    // prefetch Y chunk 0 (h[row] cols 0..63) — latency hidden under entire T phase
    float rY[16];
    {
        const float* p = h + (size_t)rIdx * HID + part * 16;
        *reinterpret_cast<float4*>(&rY[0])  = *reinterpret_cast<const float4*>(p);
        *reinterpret_cast<float4*>(&rY[4])  = *reinterpret_cast<const float4*>(p + 4);
        *reinterpret_cast<float4*>(&rY[8])  = *reinterpret_cast<const float4*>(p + 8);
        *reinterpret_cast<float4*>(&rY[12]) = *reinterpret_cast<const float4*>(p + 12);
    }

    // ---- Phase T: T = silu(time_emb) @ W_time, two barrier-free N-passes ----
    unsigned TPs[4][4][2], TPc[4][4][2];   // packed shift / scale (bf16 pairs)
    {
        f32x4 acc[4][4];
#pragma unroll
        for (int m = 0; m < 4; ++m)
#pragma unroll
            for (int n = 0; n < 4; ++n) acc[m][n] = (f32x4){0.f, 0.f, 0.f, 0.f};
#pragma unroll
        for (int kt = 0; kt < 8; ++kt) {
            bf16x8 afr[4];
#pragma unroll
            for (int m = 0; m < 4; ++m)
                afr[m] = *reinterpret_cast<const bf16x8*>(&sT[m * 16 + lr][kt * 32 + lq * 8]);
#pragma unroll
            for (int n = 0; n < 4; ++n) {
                bf16x8 bfr = *reinterpret_cast<const bf16x8*>(
                    pWtime + ((size_t)(kt * 32 + 4 * wave + n) * 64 + lane) * 8);
#pragma unroll
                for (int m = 0; m < 4; ++m)
                    acc[m][n] = __builtin_amdgcn_mfma_f32_16x16x32_bf16(afr[m], bfr, acc[m][n], 0, 0, 0);
            }
        }
#pragma unroll
        for (int n = 0; n < 4; ++n) {
            float bt = b_time[(4 * wave + n) * 16 + lr];
#pragma unroll
            for (int m = 0; m < 4; ++m) {
                TPs[m][n][0] = pk2(acc[m][n].x + bt, acc[m][n].y + bt);
                TPs[m][n][1] = pk2(acc[m][n].z + bt, acc[m][n].w + bt);
            }
        }
        // pass B: scale columns (nt 16..31)
#pragma unroll
        for (int m = 0; m < 4; ++m)
#pragma unroll
            for (int n = 0; n < 4; ++n) acc[m][n] = (f32x4){0.f, 0.f, 0.f, 0.f};
#pragma unroll
        for (int kt = 0; kt < 8; ++kt) {
            bf16x8 afr[4];
#pragma unroll
            for (int m = 0; m < 4; ++m)
                afr[m] = *reinterpret_cast<const bf16x8*>(&sT[m * 16 + lr][kt * 32 + lq * 8]);
#pragma unroll
            for (int n = 0; n < 4; ++n) {
                bf16x8 bfr = *reinterpret_cast<const bf16x8*>(
                    pWtime + ((size_t)(kt * 32 + 16 + 4 * wave + n) * 64 + lane) * 8);
#pragma unroll
                for (int m = 0; m < 4; ++m)
                    acc[m][n] = __builtin_amdgcn_mfma_f32_16x16x32_bf16(afr[m], bfr, acc[m][n], 0, 0, 0);
            }
        }
#pragma unroll
        for (int n = 0; n < 4; ++n) {
            float bt = b_time[256 + (4 * wave + n) * 16 + lr];
#pragma unroll
            for (int m = 0; m < 4; ++m) {
                TPc[m][n][0] = pk2(acc[m][n].x + bt, acc[m][n].y + bt);
                TPc[m][n][1] = pk2(acc[m][n].z + bt, acc[m][n].w + bt);
            }
        }
    }
    __syncthreads();   // B2: sT reads done, region free for sX

    // write prefetched chunk 0 into sX[0]
    {
        u32x4 w0, w1;
        w0.x = pk2(rY[0], rY[1]);   w0.y = pk2(rY[2], rY[3]);
        w0.z = pk2(rY[4], rY[5]);   w0.w = pk2(rY[6], rY[7]);
        w1.x = pk2(rY[8], rY[9]);   w1.y = pk2(rY[10], rY[11]);
        w1.z = pk2(rY[12], rY[13]); w1.w = pk2(rY[14], rY[15]);
        *reinterpret_cast<u32x4*>(&sX[0][el][part * 16]) = w0;
        *reinterpret_cast<u32x4*>(&sX[0][el][part * 16 + 8]) = w1;
    }
    __syncthreads();   // B3

    // ---- Phase Y: Y = [h[row]|h[col]|ea|dist] @ W_in, BK=64, T14 pipeline ----
    f32x4 accY[4][4];
#pragma unroll
    for (int m = 0; m < 4; ++m)
#pragma unroll
        for (int n = 0; n < 4; ++n) accY[m][n] = (f32x4){0.f, 0.f, 0.f, 0.f};

#pragma unroll
    for (int kt = 0; kt < 11; ++kt) {
        const int buf = kt & 1;
        // (1) issue next chunk's global loads early (regs)
        if (kt < 10) {
            const int kn = kt + 1;
            const float* p;
            if (kn < 4)       p = h + (size_t)rIdx * HID + kn * 64;
            else if (kn < 8)  p = h + (size_t)cIdx * HID + (kn - 4) * 64;
            else if (kn < 10) p = edge_attr + (size_t)(e0 + el) * EDIM + (kn - 8) * 64;
            else              p = dist + (size_t)(e0 + el) * DDIM;
            p += part * 16;
            *reinterpret_cast<float4*>(&rY[0])  = *reinterpret_cast<const float4*>(p);
            *reinterpret_cast<float4*>(&rY[4])  = *reinterpret_cast<const float4*>(p + 4);
            *reinterpret_cast<float4*>(&rY[8])  = *reinterpret_cast<const float4*>(p + 8);
            *reinterpret_cast<float4*>(&rY[12]) = *reinterpret_cast<const float4*>(p + 12);
        }
        // (2) ds_read current buffer + MFMA (waits only on these ds_reads)
#pragma unroll
        for (int kq = 0; kq < 2; ++kq) {
            bf16x8 afr[4];
#pragma unroll
            for (int m = 0; m < 4; ++m)
                afr[m] = *reinterpret_cast<const bf16x8*>(&sX[buf][m * 16 + lr][kq * 32 + lq * 8]);
#pragma unroll
            for (int n = 0; n < 4; ++n) {
                bf16x8 bfr = *reinterpret_cast<const bf16x8*>(
                    pWin + ((size_t)((2 * kt + kq) * 16 + 4 * wave + n) * 64 + lane) * 8);
#pragma unroll
                for (int m = 0; m < 4; ++m)
                    accY[m][n] = __builtin_amdgcn_mfma_f32_16x16x32_bf16(afr[m], bfr, accY[m][n], 0, 0, 0);
            }
        }
        // (3) convert + write next buffer late
        if (kt < 10) {
            u32x4 w0, w1;
            w0.x = pk2(rY[0], rY[1]);   w0.y = pk2(rY[2], rY[3]);
            w0.z = pk2(rY[4], rY[5]);   w0.w = pk2(rY[6], rY[7]);
            w1.x = pk2(rY[8], rY[9]);   w1.y = pk2(rY[10], rY[11]);
            w1.z = pk2(rY[12], rY[13]); w1.w = pk2(rY[14], rY[15]);
            *reinterpret_cast<u32x4*>(&sX[buf ^ 1][el][part * 16]) = w0;
            *reinterpret_cast<u32x4*>(&sX[buf ^ 1][el][part * 16 + 8]) = w1;
        }
        __syncthreads();
    }

    // + b_in
#pragma unroll
    for (int n = 0; n < 4; ++n) {
        float bi = b_in[(4 * wave + n) * 16 + lr];
#pragma unroll
        for (int m = 0; m < 4; ++m) {
            accY[m][n].x += bi; accY[m][n].y += bi; accY[m][n].z += bi; accY[m][n].w += bi;
        }
    }

    // LayerNorm stats across 256 cols (4 waves x 64 cols each)
#pragma unroll
    for (int m = 0; m < 4; ++m) {
#pragma unroll
        for (int r = 0; r < 4; ++r) {
            float v0 = accY[m][0][r], v1 = accY[m][1][r], v2 = accY[m][2][r], v3 = accY[m][3][r];
            float s1 = v0 + v1 + v2 + v3;
            float s2 = v0 * v0 + v1 * v1 + v2 * v2 + v3 * v3;
#pragma unroll
            for (int off = 1; off < 16; off <<= 1) {
                s1 += __shfl_xor(s1, off, 64);
                s2 += __shfl_xor(s2, off, 64);
            }
            if (lr == 0) {
                atomicAdd(&sSum[m * 16 + lq * 4 + r], s1);
                atomicAdd(&sSq[m * 16 + lq * 4 + r], s2);
            }
        }
    }
    __syncthreads();

    // LN + FiLM, write U (bf16) into sU (sX dead)
#pragma unroll
    for (int m = 0; m < 4; ++m) {
#pragma unroll
        for (int r = 0; r < 4; ++r) {
            int e = m * 16 + lq * 4 + r;
            float mu = sSum[e] * (1.0f / 256.0f);
            float var = sSq[e] * (1.0f / 256.0f) - mu * mu;
            float rs = rsqrtf(var + 1e-6f);
#pragma unroll
            for (int n = 0; n < 4; ++n) {
                float y = accY[m][n][r];
                float ln = (y - mu) * rs;
                unsigned ush = TPs[m][n][r >> 1];
                unsigned usc = TPc[m][n][r >> 1];
                float sh = (r & 1) ? uhi(ush) : ulo(ush);
                float sc = (r & 1) ? uhi(usc) : ulo(usc);
                sU[e][(4 * wave + n) * 16 + lr] = __float2bfloat16(ln * (1.0f + sc) + sh);
            }
        }
    }
    __syncthreads();

    // ---- Phase Z: Z = U @ W_c1 (barrier-free inner loop) ----
    f32x4 accZ[4][4];
#pragma unroll
    for (int m = 0; m < 4; ++m)
#pragma unroll
        for (int n = 0; n < 4; ++n) accZ[m][n] = (f32x4){0.f, 0.f, 0.f, 0.f};

#pragma unroll
    for (int kt = 0; kt < 8; ++kt) {
        bf16x8 afr[4];
#pragma unroll
        for (int m = 0; m < 4; ++m)
            afr[m] = *reinterpret_cast<const bf16x8*>(&sU[m * 16 + lr][kt * 32 + lq * 8]);
#pragma unroll
        for (int n = 0; n < 4; ++n) {
            bf16x8 bfr = *reinterpret_cast<const bf16x8*>(
                pWc1 + ((size_t)(kt * 16 + 4 * wave + n) * 64 + lane) * 8);
#pragma unroll
            for (int m = 0; m < 4; ++m)
                accZ[m][n] = __builtin_amdgcn_mfma_f32_16x16x32_bf16(afr[m], bfr, accZ[m][n], 0, 0, 0);
        }
    }

    // s = silu(Z + b_c1) @ W_c2 (per-edge scalar)
#pragma unroll
    for (int m = 0; m < 4; ++m) {
        float ps0 = 0.f, ps1 = 0.f, ps2 = 0.f, ps3 = 0.f;
#pragma unroll
        for (int n = 0; n < 4; ++n) {
            int colg = (4 * wave + n) * 16 + lr;
            float bc = b_c1[colg];
            float w2 = W_c2[colg];
            ps0 += silu_f(accZ[m][n][0] + bc) * w2;
            ps1 += silu_f(accZ[m][n][1] + bc) * w2;
            ps2 += silu_f(accZ[m][n][2] + bc) * w2;
            ps3 += silu_f(accZ[m][n][3] + bc) * w2;
        }
        float ps[4] = {ps0, ps1, ps2, ps3};
#pragma unroll
        for (int r = 0; r < 4; ++r) {
            float v = ps[r];
#pragma unroll
            for (int off = 1; off < 16; off <<= 1) v += __shfl_xor(v, off, 64);
            if (lr == 0) atomicAdd(&sS[m * 16 + lq * 4 + r], v);
        }
    }
    __syncthreads();

    // ---- epilogue: coord update + segment-sum atomics ----
    if (tid < 64) {
        int e = tid;
        float inv = tanhf(sS[e]);
        int rI = sRow[e], cI = sCol[e];
        float dx = pos[rI * 3 + 0] - pos[cI * 3 + 0];
        float dy = pos[rI * 3 + 1] - pos[cI * 3 + 1];
        float dz = pos[rI * 3 + 2] - pos[cI * 3 + 2];
        float nrm = sqrtf(dx * dx + dy * dy + dz * dz);
        float f = coord_scale[0] * inv / fmaxf(nrm, 1e-8f);
        atomicAdd(&out[rI * 3 + 0], dx * f);
        atomicAdd(&out[rI * 3 + 1], dy * f);
        atomicAdd(&out[rI * 3 + 2], dz * f);
    }
}

extern "C" void kernel_launch(void* const* d_in, const int* in_sizes, int n_in,
                              void* d_out, int out_size, void* d_ws, size_t ws_size,
                              hipStream_t stream) {
    const float* h          = (const float*)d_in[0];
    const float* pos        = (const float*)d_in[1];
    const float* edge_attr  = (const float*)d_in[2];
    const float* dist       = (const float*)d_in[3];
    const float* time_emb   = (const float*)d_in[4];
    const int*   edge_index = (const int*)d_in[5];
    const float* W_time     = (const float*)d_in[6];
    const float* b_time     = (const float*)d_in[7];
    const float* W_in       = (const float*)d_in[8];
    const float* b_in       = (const float*)d_in[9];
    const float* W_c1       = (const float*)d_in[10];
    const float* b_c1       = (const float*)d_in[11];
    const float* W_c2       = (const float*)d_in[12];
    const float* coord_scale= (const float*)d_in[13];
    float* out = (float*)d_out;

    unsigned short* pWin   = (unsigned short*)d_ws;                       // 704*256*2 = 360448 B
    unsigned short* pWtime = (unsigned short*)((char*)d_ws + 360448);     // 256*512*2 = 262144 B
    unsigned short* pWc1   = (unsigned short*)((char*)d_ws + 622592);     // 256*256*2 = 131072 B

    pack_weights<<<88, 256, 0, stream>>>(W_in,   pWin,   INCH, HID);
    pack_weights<<<64, 256, 0, stream>>>(W_time, pWtime, TDIM, 2 * HID);
    pack_weights<<<32, 256, 0, stream>>>(W_c1,   pWc1,   HID,  HID);
    init_out<<<(3 * NN + 255) / 256, 256, 0, stream>>>(pos, out, 3 * NN);

    edge_kernel<<<NE / 64, 256, 0, stream>>>(
        h, pos, edge_attr, dist, time_emb, edge_index,
        b_time, b_in, b_c1, W_c2, coord_scale,
        pWtime, pWin, pWc1, out);
}

// Round 3
// 912.435 us; speedup vs baseline: 1.4565x; 1.4565x over previous
//
#include <hip/hip_runtime.h>
#include <hip/hip_bf16.h>

#define NN   20000
#define NE   320000
#define HID  256
#define EDIM 128
#define DDIM 64
#define TDIM 256
#define INCH 704

typedef __attribute__((ext_vector_type(8))) short bf16x8;
typedef __attribute__((ext_vector_type(4))) float f32x4;
typedef __attribute__((ext_vector_type(4))) unsigned int u32x4;

__device__ __forceinline__ unsigned short f2bu(float x) {
    return __bfloat16_as_ushort(__float2bfloat16(x));
}
__device__ __forceinline__ unsigned pk2(float lo, float hi) {
    return (unsigned)f2bu(lo) | ((unsigned)f2bu(hi) << 16);
}
__device__ __forceinline__ float ulo(unsigned u) {
    return __bfloat162float(__ushort_as_bfloat16((unsigned short)(u & 0xffffu)));
}
__device__ __forceinline__ float uhi(unsigned u) {
    return __bfloat162float(__ushort_as_bfloat16((unsigned short)(u >> 16)));
}
__device__ __forceinline__ float silu_f(float x) {
    return x / (1.0f + __expf(-x));
}

// Pack fp32 [K][Nc] row-major weight into bf16 MFMA B-fragment order:
// frag element j of lane l of tile (kt,nt) = B[kt*32 + (l>>4)*8 + j][nt*16 + (l&15)]
// stored at dst[((kt*NT+nt)*64 + l)*8 + j]. A staging uses the same (l>>4, j)->k
// mapping, so any HW within-K-tile permutation cancels.
__global__ void pack_weights(const float* __restrict__ src, unsigned short* __restrict__ dst,
                             int K, int Nc) {
    int KT = K >> 5, NT = Nc >> 4;
    int total = KT * NT * 64;
    int idx = blockIdx.x * blockDim.x + threadIdx.x;
    if (idx >= total) return;
    int lane = idx & 63;
    int tile = idx >> 6;
    int nt = tile % NT, kt = tile / NT;
    int n = nt * 16 + (lane & 15);
    int k0 = kt * 32 + (lane >> 4) * 8;
    alignas(16) unsigned short v[8];
#pragma unroll
    for (int j = 0; j < 8; ++j) v[j] = f2bu(src[(size_t)(k0 + j) * Nc + n]);
    *reinterpret_cast<u32x4*>(dst + (size_t)idx * 8) = *reinterpret_cast<const u32x4*>(v);
}

__global__ void init_out(const float* __restrict__ pos, float* __restrict__ out, int n) {
    int i = blockIdx.x * blockDim.x + threadIdx.x;
    if (i < n) out[i] = pos[i];
}

__global__ __launch_bounds__(256, 2) void edge_kernel(
    const float* __restrict__ h, const float* __restrict__ pos,
    const float* __restrict__ edge_attr, const float* __restrict__ dist,
    const float* __restrict__ time_emb, const int* __restrict__ edge_index,
    const float* __restrict__ b_time, const float* __restrict__ b_in,
    const float* __restrict__ b_c1, const float* __restrict__ W_c2,
    const float* __restrict__ coord_scale,
    const unsigned short* __restrict__ pWtime, const unsigned short* __restrict__ pWin,
    const unsigned short* __restrict__ pWc1,
    float* __restrict__ out)
{
    // One 33792-byte region, time-multiplexed (barriers separate the three uses):
    //   sT [64][264] bf16 : silu(time_emb) staged once     (phase T)
    //   sX [2][64][72]    : double-buffered BK=64 A-chunks (phase Y)
    //   sU [64][264]      : FiLM'd LN output               (phase Z)
    __shared__ __align__(16) unsigned char smem[64 * 264 * 2];
    __hip_bfloat16 (*sT)[264]    = reinterpret_cast<__hip_bfloat16(*)[264]>(smem);
    __hip_bfloat16 (*sU)[264]    = reinterpret_cast<__hip_bfloat16(*)[264]>(smem);
    __hip_bfloat16 (*sX)[64][72] = reinterpret_cast<__hip_bfloat16(*)[64][72]>(smem);
    __shared__ float sSum[64], sSq[64], sS[64];
    __shared__ int sRow[64], sCol[64];

    const int tid = threadIdx.x;
    const int wave = tid >> 6, lane = tid & 63;
    const int lq = lane >> 4, lr = lane & 15;
    const int e0 = blockIdx.x * 64;
    const int el = tid >> 2, part = tid & 3;

    if (tid < 64) {
        sRow[tid] = edge_index[e0 + tid];
        sCol[tid] = edge_index[NE + e0 + tid];
        sSum[tid] = 0.f; sSq[tid] = 0.f; sS[tid] = 0.f;
    }

    // ---- stage silu(time_emb) block into sT (bf16), once ----
    {
        const float* p = time_emb + (size_t)(e0 + el) * TDIM + part * 64;
#pragma unroll
        for (int j = 0; j < 4; ++j) {
            float4 a = *reinterpret_cast<const float4*>(p + j * 16);
            float4 b = *reinterpret_cast<const float4*>(p + j * 16 + 4);
            float4 c = *reinterpret_cast<const float4*>(p + j * 16 + 8);
            float4 d = *reinterpret_cast<const float4*>(p + j * 16 + 12);
            u32x4 w0, w1;
            w0.x = pk2(silu_f(a.x), silu_f(a.y)); w0.y = pk2(silu_f(a.z), silu_f(a.w));
            w0.z = pk2(silu_f(b.x), silu_f(b.y)); w0.w = pk2(silu_f(b.z), silu_f(b.w));
            w1.x = pk2(silu_f(c.x), silu_f(c.y)); w1.y = pk2(silu_f(c.z), silu_f(c.w));
            w1.z = pk2(silu_f(d.x), silu_f(d.y)); w1.w = pk2(silu_f(d.z), silu_f(d.w));
            *reinterpret_cast<u32x4*>(&sT[el][part * 64 + j * 16]) = w0;
            *reinterpret_cast<u32x4*>(&sT[el][part * 64 + j * 16 + 8]) = w1;
        }
    }
    __syncthreads();   // B1: sT + sRow/sCol ready

    const int rIdx = sRow[el], cIdx = sCol[el];

    // prefetch Y chunk 0 (h[row] cols 0..63) — latency hidden under entire T phase
    float rY[16];
    {
        const float* p = h + (size_t)rIdx * HID + part * 16;
        *reinterpret_cast<float4*>(&rY[0])  = *reinterpret_cast<const float4*>(p);
        *reinterpret_cast<float4*>(&rY[4])  = *reinterpret_cast<const float4*>(p + 4);
        *reinterpret_cast<float4*>(&rY[8])  = *reinterpret_cast<const float4*>(p + 8);
        *reinterpret_cast<float4*>(&rY[12]) = *reinterpret_cast<const float4*>(p + 12);
    }

    // ---- Phase T: T = silu(time_emb) @ W_time, two barrier-free N-passes ----
    unsigned TPs[4][4][2], TPc[4][4][2];   // packed shift / scale (bf16 pairs)
    {
        f32x4 acc[4][4];
#pragma unroll
        for (int m = 0; m < 4; ++m)
#pragma unroll
            for (int n = 0; n < 4; ++n) acc[m][n] = (f32x4){0.f, 0.f, 0.f, 0.f};
#pragma unroll
        for (int kt = 0; kt < 8; ++kt) {
            bf16x8 afr[4];
#pragma unroll
            for (int m = 0; m < 4; ++m)
                afr[m] = *reinterpret_cast<const bf16x8*>(&sT[m * 16 + lr][kt * 32 + lq * 8]);
#pragma unroll
            for (int n = 0; n < 4; ++n) {
                bf16x8 bfr = *reinterpret_cast<const bf16x8*>(
                    pWtime + ((size_t)(kt * 32 + 4 * wave + n) * 64 + lane) * 8);
#pragma unroll
                for (int m = 0; m < 4; ++m)
                    acc[m][n] = __builtin_amdgcn_mfma_f32_16x16x32_bf16(afr[m], bfr, acc[m][n], 0, 0, 0);
            }
        }
#pragma unroll
        for (int n = 0; n < 4; ++n) {
            float bt = b_time[(4 * wave + n) * 16 + lr];
#pragma unroll
            for (int m = 0; m < 4; ++m) {
                TPs[m][n][0] = pk2(acc[m][n].x + bt, acc[m][n].y + bt);
                TPs[m][n][1] = pk2(acc[m][n].z + bt, acc[m][n].w + bt);
            }
        }
        // pass B: scale columns (nt 16..31)
#pragma unroll
        for (int m = 0; m < 4; ++m)
#pragma unroll
            for (int n = 0; n < 4; ++n) acc[m][n] = (f32x4){0.f, 0.f, 0.f, 0.f};
#pragma unroll
        for (int kt = 0; kt < 8; ++kt) {
            bf16x8 afr[4];
#pragma unroll
            for (int m = 0; m < 4; ++m)
                afr[m] = *reinterpret_cast<const bf16x8*>(&sT[m * 16 + lr][kt * 32 + lq * 8]);
#pragma unroll
            for (int n = 0; n < 4; ++n) {
                bf16x8 bfr = *reinterpret_cast<const bf16x8*>(
                    pWtime + ((size_t)(kt * 32 + 16 + 4 * wave + n) * 64 + lane) * 8);
#pragma unroll
                for (int m = 0; m < 4; ++m)
                    acc[m][n] = __builtin_amdgcn_mfma_f32_16x16x32_bf16(afr[m], bfr, acc[m][n], 0, 0, 0);
            }
        }
#pragma unroll
        for (int n = 0; n < 4; ++n) {
            float bt = b_time[256 + (4 * wave + n) * 16 + lr];
#pragma unroll
            for (int m = 0; m < 4; ++m) {
                TPc[m][n][0] = pk2(acc[m][n].x + bt, acc[m][n].y + bt);
                TPc[m][n][1] = pk2(acc[m][n].z + bt, acc[m][n].w + bt);
            }
        }
    }
    __syncthreads();   // B2: sT reads done, region free for sX

    // write prefetched chunk 0 into sX[0]
    {
        u32x4 w0, w1;
        w0.x = pk2(rY[0], rY[1]);   w0.y = pk2(rY[2], rY[3]);
        w0.z = pk2(rY[4], rY[5]);   w0.w = pk2(rY[6], rY[7]);
        w1.x = pk2(rY[8], rY[9]);   w1.y = pk2(rY[10], rY[11]);
        w1.z = pk2(rY[12], rY[13]); w1.w = pk2(rY[14], rY[15]);
        *reinterpret_cast<u32x4*>(&sX[0][el][part * 16]) = w0;
        *reinterpret_cast<u32x4*>(&sX[0][el][part * 16 + 8]) = w1;
    }
    __syncthreads();   // B3

    // ---- Phase Y: Y = [h[row]|h[col]|ea|dist] @ W_in, BK=64, T14 pipeline ----
    f32x4 accY[4][4];
#pragma unroll
    for (int m = 0; m < 4; ++m)
#pragma unroll
        for (int n = 0; n < 4; ++n) accY[m][n] = (f32x4){0.f, 0.f, 0.f, 0.f};

#pragma unroll
    for (int kt = 0; kt < 11; ++kt) {
        const int buf = kt & 1;
        // (1) issue next chunk's global loads early (regs)
        if (kt < 10) {
            const int kn = kt + 1;
            const float* p;
            if (kn < 4)       p = h + (size_t)rIdx * HID + kn * 64;
            else if (kn < 8)  p = h + (size_t)cIdx * HID + (kn - 4) * 64;
            else if (kn < 10) p = edge_attr + (size_t)(e0 + el) * EDIM + (kn - 8) * 64;
            else              p = dist + (size_t)(e0 + el) * DDIM;
            p += part * 16;
            *reinterpret_cast<float4*>(&rY[0])  = *reinterpret_cast<const float4*>(p);
            *reinterpret_cast<float4*>(&rY[4])  = *reinterpret_cast<const float4*>(p + 4);
            *reinterpret_cast<float4*>(&rY[8])  = *reinterpret_cast<const float4*>(p + 8);
            *reinterpret_cast<float4*>(&rY[12]) = *reinterpret_cast<const float4*>(p + 12);
        }
        // (2) ds_read current buffer + MFMA (waits only on these ds_reads)
#pragma unroll
        for (int kq = 0; kq < 2; ++kq) {
            bf16x8 afr[4];
#pragma unroll
            for (int m = 0; m < 4; ++m)
                afr[m] = *reinterpret_cast<const bf16x8*>(&sX[buf][m * 16 + lr][kq * 32 + lq * 8]);
#pragma unroll
            for (int n = 0; n < 4; ++n) {
                bf16x8 bfr = *reinterpret_cast<const bf16x8*>(
                    pWin + ((size_t)((2 * kt + kq) * 16 + 4 * wave + n) * 64 + lane) * 8);
#pragma unroll
                for (int m = 0; m < 4; ++m)
                    accY[m][n] = __builtin_amdgcn_mfma_f32_16x16x32_bf16(afr[m], bfr, accY[m][n], 0, 0, 0);
            }
        }
        // (3) convert + write next buffer late
        if (kt < 10) {
            u32x4 w0, w1;
            w0.x = pk2(rY[0], rY[1]);   w0.y = pk2(rY[2], rY[3]);
            w0.z = pk2(rY[4], rY[5]);   w0.w = pk2(rY[6], rY[7]);
            w1.x = pk2(rY[8], rY[9]);   w1.y = pk2(rY[10], rY[11]);
            w1.z = pk2(rY[12], rY[13]); w1.w = pk2(rY[14], rY[15]);
            *reinterpret_cast<u32x4*>(&sX[buf ^ 1][el][part * 16]) = w0;
            *reinterpret_cast<u32x4*>(&sX[buf ^ 1][el][part * 16 + 8]) = w1;
        }
        __syncthreads();
    }

    // + b_in
#pragma unroll
    for (int n = 0; n < 4; ++n) {
        float bi = b_in[(4 * wave + n) * 16 + lr];
#pragma unroll
        for (int m = 0; m < 4; ++m) {
            accY[m][n].x += bi; accY[m][n].y += bi; accY[m][n].z += bi; accY[m][n].w += bi;
        }
    }

    // LayerNorm stats across 256 cols (4 waves x 64 cols each)
#pragma unroll
    for (int m = 0; m < 4; ++m) {
#pragma unroll
        for (int r = 0; r < 4; ++r) {
            float v0 = accY[m][0][r], v1 = accY[m][1][r], v2 = accY[m][2][r], v3 = accY[m][3][r];
            float s1 = v0 + v1 + v2 + v3;
            float s2 = v0 * v0 + v1 * v1 + v2 * v2 + v3 * v3;
#pragma unroll
            for (int off = 1; off < 16; off <<= 1) {
                s1 += __shfl_xor(s1, off, 64);
                s2 += __shfl_xor(s2, off, 64);
            }
            if (lr == 0) {
                atomicAdd(&sSum[m * 16 + lq * 4 + r], s1);
                atomicAdd(&sSq[m * 16 + lq * 4 + r], s2);
            }
        }
    }
    __syncthreads();

    // LN + FiLM, write U (bf16) into sU (sX dead)
#pragma unroll
    for (int m = 0; m < 4; ++m) {
#pragma unroll
        for (int r = 0; r < 4; ++r) {
            int e = m * 16 + lq * 4 + r;
            float mu = sSum[e] * (1.0f / 256.0f);
            float var = sSq[e] * (1.0f / 256.0f) - mu * mu;
            float rs = rsqrtf(var + 1e-6f);
#pragma unroll
            for (int n = 0; n < 4; ++n) {
                float y = accY[m][n][r];
                float ln = (y - mu) * rs;
                unsigned ush = TPs[m][n][r >> 1];
                unsigned usc = TPc[m][n][r >> 1];
                float sh = (r & 1) ? uhi(ush) : ulo(ush);
                float sc = (r & 1) ? uhi(usc) : ulo(usc);
                sU[e][(4 * wave + n) * 16 + lr] = __float2bfloat16(ln * (1.0f + sc) + sh);
            }
        }
    }
    __syncthreads();

    // ---- Phase Z: Z = U @ W_c1 (barrier-free inner loop) ----
    f32x4 accZ[4][4];
#pragma unroll
    for (int m = 0; m < 4; ++m)
#pragma unroll
        for (int n = 0; n < 4; ++n) accZ[m][n] = (f32x4){0.f, 0.f, 0.f, 0.f};

#pragma unroll
    for (int kt = 0; kt < 8; ++kt) {
        bf16x8 afr[4];
#pragma unroll
        for (int m = 0; m < 4; ++m)
            afr[m] = *reinterpret_cast<const bf16x8*>(&sU[m * 16 + lr][kt * 32 + lq * 8]);
#pragma unroll
        for (int n = 0; n < 4; ++n) {
            bf16x8 bfr = *reinterpret_cast<const bf16x8*>(
                pWc1 + ((size_t)(kt * 16 + 4 * wave + n) * 64 + lane) * 8);
#pragma unroll
            for (int m = 0; m < 4; ++m)
                accZ[m][n] = __builtin_amdgcn_mfma_f32_16x16x32_bf16(afr[m], bfr, accZ[m][n], 0, 0, 0);
        }
    }

    // s = silu(Z + b_c1) @ W_c2 (per-edge scalar)
#pragma unroll
    for (int m = 0; m < 4; ++m) {
        float ps0 = 0.f, ps1 = 0.f, ps2 = 0.f, ps3 = 0.f;
#pragma unroll
        for (int n = 0; n < 4; ++n) {
            int colg = (4 * wave + n) * 16 + lr;
            float bc = b_c1[colg];
            float w2 = W_c2[colg];
            ps0 += silu_f(accZ[m][n][0] + bc) * w2;
            ps1 += silu_f(accZ[m][n][1] + bc) * w2;
            ps2 += silu_f(accZ[m][n][2] + bc) * w2;
            ps3 += silu_f(accZ[m][n][3] + bc) * w2;
        }
        float ps[4] = {ps0, ps1, ps2, ps3};
#pragma unroll
        for (int r = 0; r < 4; ++r) {
            float v = ps[r];
#pragma unroll
            for (int off = 1; off < 16; off <<= 1) v += __shfl_xor(v, off, 64);
            if (lr == 0) atomicAdd(&sS[m * 16 + lq * 4 + r], v);
        }
    }
    __syncthreads();

    // ---- epilogue: coord update + segment-sum atomics ----
    if (tid < 64) {
        int e = tid;
        float inv = tanhf(sS[e]);
        int rI = sRow[e], cI = sCol[e];
        float dx = pos[rI * 3 + 0] - pos[cI * 3 + 0];
        float dy = pos[rI * 3 + 1] - pos[cI * 3 + 1];
        float dz = pos[rI * 3 + 2] - pos[cI * 3 + 2];
        float nrm = sqrtf(dx * dx + dy * dy + dz * dz);
        float f = coord_scale[0] * inv / fmaxf(nrm, 1e-8f);
        atomicAdd(&out[rI * 3 + 0], dx * f);
        atomicAdd(&out[rI * 3 + 1], dy * f);
        atomicAdd(&out[rI * 3 + 2], dz * f);
    }
}

extern "C" void kernel_launch(void* const* d_in, const int* in_sizes, int n_in,
                              void* d_out, int out_size, void* d_ws, size_t ws_size,
                              hipStream_t stream) {
    const float* h          = (const float*)d_in[0];
    const float* pos        = (const float*)d_in[1];
    const float* edge_attr  = (const float*)d_in[2];
    const float* dist       = (const float*)d_in[3];
    const float* time_emb   = (const float*)d_in[4];
    const int*   edge_index = (const int*)d_in[5];
    const float* W_time     = (const float*)d_in[6];
    const float* b_time     = (const float*)d_in[7];
    const float* W_in       = (const float*)d_in[8];
    const float* b_in       = (const float*)d_in[9];
    const float* W_c1       = (const float*)d_in[10];
    const float* b_c1       = (const float*)d_in[11];
    const float* W_c2       = (const float*)d_in[12];
    const float* coord_scale= (const float*)d_in[13];
    float* out = (float*)d_out;

    unsigned short* pWin   = (unsigned short*)d_ws;                       // 704*256*2 = 360448 B
    unsigned short* pWtime = (unsigned short*)((char*)d_ws + 360448);     // 256*512*2 = 262144 B
    unsigned short* pWc1   = (unsigned short*)((char*)d_ws + 622592);     // 256*256*2 = 131072 B

    pack_weights<<<88, 256, 0, stream>>>(W_in,   pWin,   INCH, HID);
    pack_weights<<<64, 256, 0, stream>>>(W_time, pWtime, TDIM, 2 * HID);
    pack_weights<<<32, 256, 0, stream>>>(W_c1,   pWc1,   HID,  HID);
    init_out<<<(3 * NN + 255) / 256, 256, 0, stream>>>(pos, out, 3 * NN);

    edge_kernel<<<NE / 64, 256, 0, stream>>>(
        h, pos, edge_attr, dist, time_emb, edge_index,
        b_time, b_in, b_c1, W_c2, coord_scale,
        pWtime, pWin, pWc1, out);
}

// Round 4
// 868.435 us; speedup vs baseline: 1.5303x; 1.0507x over previous
//
#include <hip/hip_runtime.h>
#include <hip/hip_bf16.h>

#define NN   20000
#define NE   320000
#define HID  256
#define EDIM 128
#define DDIM 64
#define TDIM 256
#define INCH 704

typedef __attribute__((ext_vector_type(8))) short bf16x8;
typedef __attribute__((ext_vector_type(4))) float f32x4;
typedef __attribute__((ext_vector_type(4))) unsigned int u32x4;

__device__ __forceinline__ unsigned short f2bu(float x) {
    return __bfloat16_as_ushort(__float2bfloat16(x));
}
__device__ __forceinline__ unsigned pk2(float lo, float hi) {
    return (unsigned)f2bu(lo) | ((unsigned)f2bu(hi) << 16);
}
__device__ __forceinline__ float silu_f(float x) {
    return x / (1.0f + __expf(-x));
}

// Pack fp32 [K][Nc] row-major weight into bf16 MFMA B-fragment order:
// frag element j of lane l of tile (kt,nt) = B[kt*32 + (l>>4)*8 + j][nt*16 + (l&15)]
// stored at dst[((kt*NT+nt)*64 + l)*8 + j]. A staging uses the same (l>>4, j)->k
// mapping, so any HW within-K-tile permutation cancels.
__global__ void pack_weights(const float* __restrict__ src, unsigned short* __restrict__ dst,
                             int K, int Nc) {
    int KT = K >> 5, NT = Nc >> 4;
    int total = KT * NT * 64;
    int idx = blockIdx.x * blockDim.x + threadIdx.x;
    if (idx >= total) return;
    int lane = idx & 63;
    int tile = idx >> 6;
    int nt = tile % NT, kt = tile / NT;
    int n = nt * 16 + (lane & 15);
    int k0 = kt * 32 + (lane >> 4) * 8;
    alignas(16) unsigned short v[8];
#pragma unroll
    for (int j = 0; j < 8; ++j) v[j] = f2bu(src[(size_t)(k0 + j) * Nc + n]);
    *reinterpret_cast<u32x4*>(dst + (size_t)idx * 8) = *reinterpret_cast<const u32x4*>(v);
}

__global__ void init_out(const float* __restrict__ pos, float* __restrict__ out, int n) {
    int i = blockIdx.x * blockDim.x + threadIdx.x;
    if (i < n) out[i] = pos[i];
}

__global__ __launch_bounds__(256, 2) void edge_kernel(
    const float* __restrict__ h, const float* __restrict__ pos,
    const float* __restrict__ edge_attr, const float* __restrict__ dist,
    const float* __restrict__ time_emb, const int* __restrict__ edge_index,
    const float* __restrict__ b_time, const float* __restrict__ b_in,
    const float* __restrict__ b_c1, const float* __restrict__ W_c2,
    const float* __restrict__ coord_scale,
    const unsigned short* __restrict__ pWtime, const unsigned short* __restrict__ pWin,
    const unsigned short* __restrict__ pWc1,
    float* __restrict__ out)
{
    // Region 1 (persistent): sT[64][264] = silu(time_emb) bf16, staged once, read by both T passes.
    // Region 2 (time-muxed): sX[2][64][72] double-buffered Y A-chunks, then sU[64][264].
    __shared__ __align__(16) unsigned char smemT[64 * 264 * 2];
    __shared__ __align__(16) unsigned char smem2[64 * 264 * 2];
    __hip_bfloat16 (*sT)[264]    = reinterpret_cast<__hip_bfloat16(*)[264]>(smemT);
    __hip_bfloat16 (*sU)[264]    = reinterpret_cast<__hip_bfloat16(*)[264]>(smem2);
    __hip_bfloat16 (*sX)[64][72] = reinterpret_cast<__hip_bfloat16(*)[64][72]>(smem2);
    __shared__ float sSum[64], sSq[64], sS[64];
    __shared__ int sRow[64], sCol[64];

    const int tid = threadIdx.x;
    const int wave = tid >> 6, lane = tid & 63;
    const int lq = lane >> 4, lr = lane & 15;
    const int e0 = blockIdx.x * 64;
    const int el = tid >> 2, part = tid & 3;

    // direct index loads (no barrier dependency) so the h-gather prefetch can issue immediately
    const int rIdx = edge_index[e0 + el];
    const int cIdx = edge_index[NE + e0 + el];

    // prefetch Y chunk 0 (h[rIdx] cols 0..63) — latency hides under sT staging
    float rY[16];
    {
        const float* p = h + (size_t)rIdx * HID + part * 16;
        *reinterpret_cast<float4*>(&rY[0])  = *reinterpret_cast<const float4*>(p);
        *reinterpret_cast<float4*>(&rY[4])  = *reinterpret_cast<const float4*>(p + 4);
        *reinterpret_cast<float4*>(&rY[8])  = *reinterpret_cast<const float4*>(p + 8);
        *reinterpret_cast<float4*>(&rY[12]) = *reinterpret_cast<const float4*>(p + 12);
    }

    if (tid < 64) {
        sRow[tid] = edge_index[e0 + tid];
        sCol[tid] = edge_index[NE + e0 + tid];
        sSum[tid] = 0.f; sSq[tid] = 0.f; sS[tid] = 0.f;
    }

    // ---- stage silu(time_emb) into sT (bf16), once ----
    {
        const float* p = time_emb + (size_t)(e0 + el) * TDIM + part * 64;
#pragma unroll
        for (int j = 0; j < 4; ++j) {
            float4 a = *reinterpret_cast<const float4*>(p + j * 16);
            float4 b = *reinterpret_cast<const float4*>(p + j * 16 + 4);
            float4 c = *reinterpret_cast<const float4*>(p + j * 16 + 8);
            float4 d = *reinterpret_cast<const float4*>(p + j * 16 + 12);
            u32x4 w0, w1;
            w0.x = pk2(silu_f(a.x), silu_f(a.y)); w0.y = pk2(silu_f(a.z), silu_f(a.w));
            w0.z = pk2(silu_f(b.x), silu_f(b.y)); w0.w = pk2(silu_f(b.z), silu_f(b.w));
            w1.x = pk2(silu_f(c.x), silu_f(c.y)); w1.y = pk2(silu_f(c.z), silu_f(c.w));
            w1.z = pk2(silu_f(d.x), silu_f(d.y)); w1.w = pk2(silu_f(d.z), silu_f(d.w));
            *reinterpret_cast<u32x4*>(&sT[el][part * 64 + j * 16]) = w0;
            *reinterpret_cast<u32x4*>(&sT[el][part * 64 + j * 16 + 8]) = w1;
        }
    }

    // write prefetched chunk 0 into sX[0]
    {
        u32x4 w0, w1;
        w0.x = pk2(rY[0], rY[1]);   w0.y = pk2(rY[2], rY[3]);
        w0.z = pk2(rY[4], rY[5]);   w0.w = pk2(rY[6], rY[7]);
        w1.x = pk2(rY[8], rY[9]);   w1.y = pk2(rY[10], rY[11]);
        w1.z = pk2(rY[12], rY[13]); w1.w = pk2(rY[14], rY[15]);
        *reinterpret_cast<u32x4*>(&sX[0][el][part * 16]) = w0;
        *reinterpret_cast<u32x4*>(&sX[0][el][part * 16 + 8]) = w1;
    }
    __syncthreads();   // B1: sT, sX[0], sRow/sCol, zeroed stats all ready

    // ---- Phase Y: Y = [h[row]|h[col]|ea|dist] @ W_in, BK=64, reg-staged T14 pipeline ----
    f32x4 accY[4][4];
#pragma unroll
    for (int m = 0; m < 4; ++m)
#pragma unroll
        for (int n = 0; n < 4; ++n) accY[m][n] = (f32x4){0.f, 0.f, 0.f, 0.f};

#pragma unroll
    for (int kt = 0; kt < 11; ++kt) {
        const int buf = kt & 1;
        // (1) issue next chunk's global loads early (regs)
        if (kt < 10) {
            const int kn = kt + 1;
            const float* p;
            if (kn < 4)       p = h + (size_t)rIdx * HID + kn * 64;
            else if (kn < 8)  p = h + (size_t)cIdx * HID + (kn - 4) * 64;
            else if (kn < 10) p = edge_attr + (size_t)(e0 + el) * EDIM + (kn - 8) * 64;
            else              p = dist + (size_t)(e0 + el) * DDIM;
            p += part * 16;
            *reinterpret_cast<float4*>(&rY[0])  = *reinterpret_cast<const float4*>(p);
            *reinterpret_cast<float4*>(&rY[4])  = *reinterpret_cast<const float4*>(p + 4);
            *reinterpret_cast<float4*>(&rY[8])  = *reinterpret_cast<const float4*>(p + 8);
            *reinterpret_cast<float4*>(&rY[12]) = *reinterpret_cast<const float4*>(p + 12);
        }
        // (2) ds_read current buffer + MFMA
#pragma unroll
        for (int kq = 0; kq < 2; ++kq) {
            bf16x8 afr[4];
#pragma unroll
            for (int m = 0; m < 4; ++m)
                afr[m] = *reinterpret_cast<const bf16x8*>(&sX[buf][m * 16 + lr][kq * 32 + lq * 8]);
#pragma unroll
            for (int n = 0; n < 4; ++n) {
                bf16x8 bfr = *reinterpret_cast<const bf16x8*>(
                    pWin + ((size_t)((2 * kt + kq) * 16 + 4 * wave + n) * 64 + lane) * 8);
#pragma unroll
                for (int m = 0; m < 4; ++m)
                    accY[m][n] = __builtin_amdgcn_mfma_f32_16x16x32_bf16(afr[m], bfr, accY[m][n], 0, 0, 0);
            }
        }
        // (3) convert + write next buffer late
        if (kt < 10) {
            u32x4 w0, w1;
            w0.x = pk2(rY[0], rY[1]);   w0.y = pk2(rY[2], rY[3]);
            w0.z = pk2(rY[4], rY[5]);   w0.w = pk2(rY[6], rY[7]);
            w1.x = pk2(rY[8], rY[9]);   w1.y = pk2(rY[10], rY[11]);
            w1.z = pk2(rY[12], rY[13]); w1.w = pk2(rY[14], rY[15]);
            *reinterpret_cast<u32x4*>(&sX[buf ^ 1][el][part * 16]) = w0;
            *reinterpret_cast<u32x4*>(&sX[buf ^ 1][el][part * 16 + 8]) = w1;
        }
        __syncthreads();
    }
    // after the loop's final barrier, no wave touches sX again -> region free for sU

    // + b_in
#pragma unroll
    for (int n = 0; n < 4; ++n) {
        float bi = b_in[(4 * wave + n) * 16 + lr];
#pragma unroll
        for (int m = 0; m < 4; ++m) {
            accY[m][n].x += bi; accY[m][n].y += bi; accY[m][n].z += bi; accY[m][n].w += bi;
        }
    }

    // LayerNorm stats across 256 cols (4 waves x 64 cols each)
#pragma unroll
    for (int m = 0; m < 4; ++m) {
#pragma unroll
        for (int r = 0; r < 4; ++r) {
            float v0 = accY[m][0][r], v1 = accY[m][1][r], v2 = accY[m][2][r], v3 = accY[m][3][r];
            float s1 = v0 + v1 + v2 + v3;
            float s2 = v0 * v0 + v1 * v1 + v2 * v2 + v3 * v3;
#pragma unroll
            for (int off = 1; off < 16; off <<= 1) {
                s1 += __shfl_xor(s1, off, 64);
                s2 += __shfl_xor(s2, off, 64);
            }
            if (lr == 0) {
                atomicAdd(&sSum[m * 16 + lq * 4 + r], s1);
                atomicAdd(&sSq[m * 16 + lq * 4 + r], s2);
            }
        }
    }
    __syncthreads();

    // normalize in place: accY <- LN(Y)
#pragma unroll
    for (int m = 0; m < 4; ++m) {
#pragma unroll
        for (int r = 0; r < 4; ++r) {
            int e = m * 16 + lq * 4 + r;
            float mu = sSum[e] * (1.0f / 256.0f);
            float var = sSq[e] * (1.0f / 256.0f) - mu * mu;
            float rs = rsqrtf(var + 1e-6f);
#pragma unroll
            for (int n = 0; n < 4; ++n)
                accY[m][n][r] = (accY[m][n][r] - mu) * rs;
        }
    }

    // ---- Phase T (pass 1, scale cols 256..511): accY *= (1 + scale) ----
    {
        f32x4 acc2[4][4];
#pragma unroll
        for (int m = 0; m < 4; ++m)
#pragma unroll
            for (int n = 0; n < 4; ++n) acc2[m][n] = (f32x4){0.f, 0.f, 0.f, 0.f};
#pragma unroll
        for (int kt = 0; kt < 8; ++kt) {
            bf16x8 afr[4];
#pragma unroll
            for (int m = 0; m < 4; ++m)
                afr[m] = *reinterpret_cast<const bf16x8*>(&sT[m * 16 + lr][kt * 32 + lq * 8]);
#pragma unroll
            for (int n = 0; n < 4; ++n) {
                bf16x8 bfr = *reinterpret_cast<const bf16x8*>(
                    pWtime + ((size_t)(kt * 32 + 16 + 4 * wave + n) * 64 + lane) * 8);
#pragma unroll
                for (int m = 0; m < 4; ++m)
                    acc2[m][n] = __builtin_amdgcn_mfma_f32_16x16x32_bf16(afr[m], bfr, acc2[m][n], 0, 0, 0);
            }
        }
#pragma unroll
        for (int n = 0; n < 4; ++n) {
            float btc = b_time[256 + (4 * wave + n) * 16 + lr];
#pragma unroll
            for (int m = 0; m < 4; ++m) {
#pragma unroll
                for (int r = 0; r < 4; ++r)
                    accY[m][n][r] *= (1.0f + btc + acc2[m][n][r]);
            }
        }
    }

    // ---- Phase T (pass 2, shift cols 0..255): accY += shift ----
    {
        f32x4 acc2[4][4];
#pragma unroll
        for (int m = 0; m < 4; ++m)
#pragma unroll
            for (int n = 0; n < 4; ++n) acc2[m][n] = (f32x4){0.f, 0.f, 0.f, 0.f};
#pragma unroll
        for (int kt = 0; kt < 8; ++kt) {
            bf16x8 afr[4];
#pragma unroll
            for (int m = 0; m < 4; ++m)
                afr[m] = *reinterpret_cast<const bf16x8*>(&sT[m * 16 + lr][kt * 32 + lq * 8]);
#pragma unroll
            for (int n = 0; n < 4; ++n) {
                bf16x8 bfr = *reinterpret_cast<const bf16x8*>(
                    pWtime + ((size_t)(kt * 32 + 4 * wave + n) * 64 + lane) * 8);
#pragma unroll
                for (int m = 0; m < 4; ++m)
                    acc2[m][n] = __builtin_amdgcn_mfma_f32_16x16x32_bf16(afr[m], bfr, acc2[m][n], 0, 0, 0);
            }
        }
#pragma unroll
        for (int n = 0; n < 4; ++n) {
            float bts = b_time[(4 * wave + n) * 16 + lr];
#pragma unroll
            for (int m = 0; m < 4; ++m) {
#pragma unroll
                for (int r = 0; r < 4; ++r)
                    accY[m][n][r] += bts + acc2[m][n][r];
            }
        }
    }

    // write U (bf16) into sU (sX region dead)
#pragma unroll
    for (int m = 0; m < 4; ++m) {
#pragma unroll
        for (int r = 0; r < 4; ++r) {
            int e = m * 16 + lq * 4 + r;
#pragma unroll
            for (int n = 0; n < 4; ++n)
                sU[e][(4 * wave + n) * 16 + lr] = __float2bfloat16(accY[m][n][r]);
        }
    }
    __syncthreads();

    // ---- Phase Z: Z = U @ W_c1 (barrier-free inner loop) ----
    f32x4 accZ[4][4];
#pragma unroll
    for (int m = 0; m < 4; ++m)
#pragma unroll
        for (int n = 0; n < 4; ++n) accZ[m][n] = (f32x4){0.f, 0.f, 0.f, 0.f};

#pragma unroll
    for (int kt = 0; kt < 8; ++kt) {
        bf16x8 afr[4];
#pragma unroll
        for (int m = 0; m < 4; ++m)
            afr[m] = *reinterpret_cast<const bf16x8*>(&sU[m * 16 + lr][kt * 32 + lq * 8]);
#pragma unroll
        for (int n = 0; n < 4; ++n) {
            bf16x8 bfr = *reinterpret_cast<const bf16x8*>(
                pWc1 + ((size_t)(kt * 16 + 4 * wave + n) * 64 + lane) * 8);
#pragma unroll
            for (int m = 0; m < 4; ++m)
                accZ[m][n] = __builtin_amdgcn_mfma_f32_16x16x32_bf16(afr[m], bfr, accZ[m][n], 0, 0, 0);
        }
    }

    // s = silu(Z + b_c1) @ W_c2 (per-edge scalar)
#pragma unroll
    for (int m = 0; m < 4; ++m) {
        float ps0 = 0.f, ps1 = 0.f, ps2 = 0.f, ps3 = 0.f;
#pragma unroll
        for (int n = 0; n < 4; ++n) {
            int colg = (4 * wave + n) * 16 + lr;
            float bc = b_c1[colg];
            float w2 = W_c2[colg];
            ps0 += silu_f(accZ[m][n][0] + bc) * w2;
            ps1 += silu_f(accZ[m][n][1] + bc) * w2;
            ps2 += silu_f(accZ[m][n][2] + bc) * w2;
            ps3 += silu_f(accZ[m][n][3] + bc) * w2;
        }
        float ps[4] = {ps0, ps1, ps2, ps3};
#pragma unroll
        for (int r = 0; r < 4; ++r) {
            float v = ps[r];
#pragma unroll
            for (int off = 1; off < 16; off <<= 1) v += __shfl_xor(v, off, 64);
            if (lr == 0) atomicAdd(&sS[m * 16 + lq * 4 + r], v);
        }
    }
    __syncthreads();

    // ---- epilogue: coord update + segment-sum atomics ----
    if (tid < 64) {
        int e = tid;
        float inv = tanhf(sS[e]);
        int rI = sRow[e], cI = sCol[e];
        float dx = pos[rI * 3 + 0] - pos[cI * 3 + 0];
        float dy = pos[rI * 3 + 1] - pos[cI * 3 + 1];
        float dz = pos[rI * 3 + 2] - pos[cI * 3 + 2];
        float nrm = sqrtf(dx * dx + dy * dy + dz * dz);
        float f = coord_scale[0] * inv / fmaxf(nrm, 1e-8f);
        atomicAdd(&out[rI * 3 + 0], dx * f);
        atomicAdd(&out[rI * 3 + 1], dy * f);
        atomicAdd(&out[rI * 3 + 2], dz * f);
    }
}

extern "C" void kernel_launch(void* const* d_in, const int* in_sizes, int n_in,
                              void* d_out, int out_size, void* d_ws, size_t ws_size,
                              hipStream_t stream) {
    const float* h          = (const float*)d_in[0];
    const float* pos        = (const float*)d_in[1];
    const float* edge_attr  = (const float*)d_in[2];
    const float* dist       = (const float*)d_in[3];
    const float* time_emb   = (const float*)d_in[4];
    const int*   edge_index = (const int*)d_in[5];
    const float* W_time     = (const float*)d_in[6];
    const float* b_time     = (const float*)d_in[7];
    const float* W_in       = (const float*)d_in[8];
    const float* b_in       = (const float*)d_in[9];
    const float* W_c1       = (const float*)d_in[10];
    const float* b_c1       = (const float*)d_in[11];
    const float* W_c2       = (const float*)d_in[12];
    const float* coord_scale= (const float*)d_in[13];
    float* out = (float*)d_out;

    unsigned short* pWin   = (unsigned short*)d_ws;                       // 704*256*2 = 360448 B
    unsigned short* pWtime = (unsigned short*)((char*)d_ws + 360448);     // 256*512*2 = 262144 B
    unsigned short* pWc1   = (unsigned short*)((char*)d_ws + 622592);     // 256*256*2 = 131072 B

    pack_weights<<<88, 256, 0, stream>>>(W_in,   pWin,   INCH, HID);
    pack_weights<<<64, 256, 0, stream>>>(W_time, pWtime, TDIM, 2 * HID);
    pack_weights<<<32, 256, 0, stream>>>(W_c1,   pWc1,   HID,  HID);
    init_out<<<(3 * NN + 255) / 256, 256, 0, stream>>>(pos, out, 3 * NN);

    edge_kernel<<<NE / 64, 256, 0, stream>>>(
        h, pos, edge_attr, dist, time_emb, edge_index,
        b_time, b_in, b_c1, W_c2, coord_scale,
        pWtime, pWin, pWc1, out);
}

// Round 5
// 771.292 us; speedup vs baseline: 1.7231x; 1.1259x over previous
//
#include <hip/hip_runtime.h>
#include <hip/hip_bf16.h>

#define NN   20000
#define NE   320000
#define HID  256
#define EDIM 128
#define DDIM 64
#define TDIM 256
#define INCH 704

typedef __attribute__((ext_vector_type(8))) short bf16x8;
typedef __attribute__((ext_vector_type(4))) float f32x4;
typedef __attribute__((ext_vector_type(4))) unsigned int u32x4;

__device__ __forceinline__ unsigned short f2bu(float x) {
    return __bfloat16_as_ushort(__float2bfloat16(x));
}
__device__ __forceinline__ unsigned pk2(float lo, float hi) {
    return (unsigned)f2bu(lo) | ((unsigned)f2bu(hi) << 16);
}
__device__ __forceinline__ float silu_f(float x) {
    return x / (1.0f + __expf(-x));
}

// Pack fp32 [K][Nc] row-major weight into bf16 MFMA B-fragment order:
// frag element j of lane l of tile (kt,nt) = B[kt*32 + (l>>4)*8 + j][nt*16 + (l&15)]
// stored at dst[((kt*NT+nt)*64 + l)*8 + j]. A staging uses the same (l>>4, j)->k
// mapping, so any HW within-K-tile permutation cancels.
__global__ void pack_weights(const float* __restrict__ src, unsigned short* __restrict__ dst,
                             int K, int Nc) {
    int KT = K >> 5, NT = Nc >> 4;
    int total = KT * NT * 64;
    int idx = blockIdx.x * blockDim.x + threadIdx.x;
    if (idx >= total) return;
    int lane = idx & 63;
    int tile = idx >> 6;
    int nt = tile % NT, kt = tile / NT;
    int n = nt * 16 + (lane & 15);
    int k0 = kt * 32 + (lane >> 4) * 8;
    alignas(16) unsigned short v[8];
#pragma unroll
    for (int j = 0; j < 8; ++j) v[j] = f2bu(src[(size_t)(k0 + j) * Nc + n]);
    *reinterpret_cast<u32x4*>(dst + (size_t)idx * 8) = *reinterpret_cast<const u32x4*>(v);
}

__global__ void init_out(const float* __restrict__ pos, float* __restrict__ out, int n) {
    int i = blockIdx.x * blockDim.x + threadIdx.x;
    if (i < n) out[i] = pos[i];
}

__global__ __launch_bounds__(256, 2) void edge_kernel(
    const float* __restrict__ h, const float* __restrict__ pos,
    const float* __restrict__ edge_attr, const float* __restrict__ dist,
    const float* __restrict__ time_emb, const int* __restrict__ edge_index,
    const float* __restrict__ b_time, const float* __restrict__ b_in,
    const float* __restrict__ b_c1, const float* __restrict__ W_c2,
    const float* __restrict__ coord_scale,
    const unsigned short* __restrict__ pWtime, const unsigned short* __restrict__ pWin,
    const unsigned short* __restrict__ pWc1,
    float* __restrict__ out)
{
    // Region 1 (persistent): sT[64][264] = silu(time_emb) bf16, staged once, read by both T passes.
    // Region 2 (time-muxed): sX[2][64][72] double-buffered Y A-chunks, then sU[64][264].
    __shared__ __align__(16) unsigned char smemT[64 * 264 * 2];
    __shared__ __align__(16) unsigned char smem2[64 * 264 * 2];
    __hip_bfloat16 (*sT)[264]    = reinterpret_cast<__hip_bfloat16(*)[264]>(smemT);
    __hip_bfloat16 (*sU)[264]    = reinterpret_cast<__hip_bfloat16(*)[264]>(smem2);
    __hip_bfloat16 (*sX)[64][72] = reinterpret_cast<__hip_bfloat16(*)[64][72]>(smem2);
    __shared__ float sSum[64], sSq[64], sS[64];
    __shared__ int sRow[64], sCol[64];

    const int tid = threadIdx.x;
    const int wave = tid >> 6, lane = tid & 63;
    const int lq = lane >> 4, lr = lane & 15;
    const int e0 = blockIdx.x * 64;
    const int el = tid >> 2, part = tid & 3;

    // direct index loads (no barrier dependency) so the h-gather prefetch can issue immediately
    const int rIdx = edge_index[e0 + el];
    const int cIdx = edge_index[NE + e0 + el];

    // prefetch Y chunk 0 (h[rIdx] cols 0..63) — latency hides under sT staging
    float rY[16];
    {
        const float* p = h + (size_t)rIdx * HID + part * 16;
        *reinterpret_cast<float4*>(&rY[0])  = *reinterpret_cast<const float4*>(p);
        *reinterpret_cast<float4*>(&rY[4])  = *reinterpret_cast<const float4*>(p + 4);
        *reinterpret_cast<float4*>(&rY[8])  = *reinterpret_cast<const float4*>(p + 8);
        *reinterpret_cast<float4*>(&rY[12]) = *reinterpret_cast<const float4*>(p + 12);
    }

    if (tid < 64) {
        sRow[tid] = edge_index[e0 + tid];
        sCol[tid] = edge_index[NE + e0 + tid];
        sSum[tid] = 0.f; sSq[tid] = 0.f; sS[tid] = 0.f;
    }

    // ---- stage silu(time_emb) into sT (bf16), once ----
    {
        const float* p = time_emb + (size_t)(e0 + el) * TDIM + part * 64;
#pragma unroll
        for (int j = 0; j < 4; ++j) {
            float4 a = *reinterpret_cast<const float4*>(p + j * 16);
            float4 b = *reinterpret_cast<const float4*>(p + j * 16 + 4);
            float4 c = *reinterpret_cast<const float4*>(p + j * 16 + 8);
            float4 d = *reinterpret_cast<const float4*>(p + j * 16 + 12);
            u32x4 w0, w1;
            w0.x = pk2(silu_f(a.x), silu_f(a.y)); w0.y = pk2(silu_f(a.z), silu_f(a.w));
            w0.z = pk2(silu_f(b.x), silu_f(b.y)); w0.w = pk2(silu_f(b.z), silu_f(b.w));
            w1.x = pk2(silu_f(c.x), silu_f(c.y)); w1.y = pk2(silu_f(c.z), silu_f(c.w));
            w1.z = pk2(silu_f(d.x), silu_f(d.y)); w1.w = pk2(silu_f(d.z), silu_f(d.w));
            *reinterpret_cast<u32x4*>(&sT[el][part * 64 + j * 16]) = w0;
            *reinterpret_cast<u32x4*>(&sT[el][part * 64 + j * 16 + 8]) = w1;
        }
    }

    // write prefetched chunk 0 into sX[0]
    {
        u32x4 w0, w1;
        w0.x = pk2(rY[0], rY[1]);   w0.y = pk2(rY[2], rY[3]);
        w0.z = pk2(rY[4], rY[5]);   w0.w = pk2(rY[6], rY[7]);
        w1.x = pk2(rY[8], rY[9]);   w1.y = pk2(rY[10], rY[11]);
        w1.z = pk2(rY[12], rY[13]); w1.w = pk2(rY[14], rY[15]);
        *reinterpret_cast<u32x4*>(&sX[0][el][part * 16]) = w0;
        *reinterpret_cast<u32x4*>(&sX[0][el][part * 16 + 8]) = w1;
    }
    __syncthreads();   // B1: sT, sX[0], sRow/sCol, zeroed stats all ready

    // ---- Phase Y: Y = [h[row]|h[col]|ea|dist] @ W_in, BK=64, reg-staged T14 pipeline ----
    f32x4 accY[4][4];
#pragma unroll
    for (int m = 0; m < 4; ++m)
#pragma unroll
        for (int n = 0; n < 4; ++n) accY[m][n] = (f32x4){0.f, 0.f, 0.f, 0.f};

#pragma unroll 2
    for (int kt = 0; kt < 11; ++kt) {
        const int buf = kt & 1;
        // (1) issue next chunk's global loads early (regs)
        if (kt < 10) {
            const int kn = kt + 1;
            const float* p;
            if (kn < 4)       p = h + (size_t)rIdx * HID + kn * 64;
            else if (kn < 8)  p = h + (size_t)cIdx * HID + (kn - 4) * 64;
            else if (kn < 10) p = edge_attr + (size_t)(e0 + el) * EDIM + (kn - 8) * 64;
            else              p = dist + (size_t)(e0 + el) * DDIM;
            p += part * 16;
            *reinterpret_cast<float4*>(&rY[0])  = *reinterpret_cast<const float4*>(p);
            *reinterpret_cast<float4*>(&rY[4])  = *reinterpret_cast<const float4*>(p + 4);
            *reinterpret_cast<float4*>(&rY[8])  = *reinterpret_cast<const float4*>(p + 8);
            *reinterpret_cast<float4*>(&rY[12]) = *reinterpret_cast<const float4*>(p + 12);
        }
        // (2) ds_read current buffer + MFMA
#pragma unroll
        for (int kq = 0; kq < 2; ++kq) {
            bf16x8 afr[4];
#pragma unroll
            for (int m = 0; m < 4; ++m)
                afr[m] = *reinterpret_cast<const bf16x8*>(&sX[buf][m * 16 + lr][kq * 32 + lq * 8]);
#pragma unroll
            for (int n = 0; n < 4; ++n) {
                bf16x8 bfr = *reinterpret_cast<const bf16x8*>(
                    pWin + ((size_t)((2 * kt + kq) * 16 + 4 * wave + n) * 64 + lane) * 8);
#pragma unroll
                for (int m = 0; m < 4; ++m)
                    accY[m][n] = __builtin_amdgcn_mfma_f32_16x16x32_bf16(afr[m], bfr, accY[m][n], 0, 0, 0);
            }
        }
        // (3) convert + write next buffer late
        if (kt < 10) {
            u32x4 w0, w1;
            w0.x = pk2(rY[0], rY[1]);   w0.y = pk2(rY[2], rY[3]);
            w0.z = pk2(rY[4], rY[5]);   w0.w = pk2(rY[6], rY[7]);
            w1.x = pk2(rY[8], rY[9]);   w1.y = pk2(rY[10], rY[11]);
            w1.z = pk2(rY[12], rY[13]); w1.w = pk2(rY[14], rY[15]);
            *reinterpret_cast<u32x4*>(&sX[buf ^ 1][el][part * 16]) = w0;
            *reinterpret_cast<u32x4*>(&sX[buf ^ 1][el][part * 16 + 8]) = w1;
        }
        __syncthreads();
    }
    // after the loop's final barrier, no wave touches sX again -> region free for sU

    // + b_in
#pragma unroll
    for (int n = 0; n < 4; ++n) {
        float bi = b_in[(4 * wave + n) * 16 + lr];
#pragma unroll
        for (int m = 0; m < 4; ++m) {
            accY[m][n].x += bi; accY[m][n].y += bi; accY[m][n].z += bi; accY[m][n].w += bi;
        }
    }

    // LayerNorm stats across 256 cols (4 waves x 64 cols each)
#pragma unroll
    for (int m = 0; m < 4; ++m) {
#pragma unroll
        for (int r = 0; r < 4; ++r) {
            float v0 = accY[m][0][r], v1 = accY[m][1][r], v2 = accY[m][2][r], v3 = accY[m][3][r];
            float s1 = v0 + v1 + v2 + v3;
            float s2 = v0 * v0 + v1 * v1 + v2 * v2 + v3 * v3;
#pragma unroll
            for (int off = 1; off < 16; off <<= 1) {
                s1 += __shfl_xor(s1, off, 64);
                s2 += __shfl_xor(s2, off, 64);
            }
            if (lr == 0) {
                atomicAdd(&sSum[m * 16 + lq * 4 + r], s1);
                atomicAdd(&sSq[m * 16 + lq * 4 + r], s2);
            }
        }
    }
    __syncthreads();

    // normalize in place: accY <- LN(Y)
#pragma unroll
    for (int m = 0; m < 4; ++m) {
#pragma unroll
        for (int r = 0; r < 4; ++r) {
            int e = m * 16 + lq * 4 + r;
            float mu = sSum[e] * (1.0f / 256.0f);
            float var = sSq[e] * (1.0f / 256.0f) - mu * mu;
            float rs = rsqrtf(var + 1e-6f);
#pragma unroll
            for (int n = 0; n < 4; ++n)
                accY[m][n][r] = (accY[m][n][r] - mu) * rs;
        }
    }

    // ---- Phase T: FiLM via two passes (scale, shift), each m-split into halves
    //      to cap accumulator pressure at accY(64) + acc2(32). ----
#pragma unroll
    for (int pass = 0; pass < 2; ++pass) {
        // pass 0: scale (W_time cols 256..511) -> accY *= (1 + b + t)
        // pass 1: shift (W_time cols 0..255)   -> accY += b + t
#pragma unroll
        for (int mh = 0; mh < 2; ++mh) {
            f32x4 acc2[2][4];
#pragma unroll
            for (int mm = 0; mm < 2; ++mm)
#pragma unroll
                for (int n = 0; n < 4; ++n) acc2[mm][n] = (f32x4){0.f, 0.f, 0.f, 0.f};
#pragma unroll
            for (int kt = 0; kt < 8; ++kt) {
                bf16x8 afr[2];
#pragma unroll
                for (int mm = 0; mm < 2; ++mm)
                    afr[mm] = *reinterpret_cast<const bf16x8*>(
                        &sT[(2 * mh + mm) * 16 + lr][kt * 32 + lq * 8]);
#pragma unroll
                for (int n = 0; n < 4; ++n) {
                    int ncol = (pass == 0) ? (16 + 4 * wave + n) : (4 * wave + n);
                    bf16x8 bfr = *reinterpret_cast<const bf16x8*>(
                        pWtime + ((size_t)(kt * 32 + ncol) * 64 + lane) * 8);
#pragma unroll
                    for (int mm = 0; mm < 2; ++mm)
                        acc2[mm][n] = __builtin_amdgcn_mfma_f32_16x16x32_bf16(afr[mm], bfr, acc2[mm][n], 0, 0, 0);
                }
            }
#pragma unroll
            for (int n = 0; n < 4; ++n) {
                float bt = (pass == 0) ? b_time[256 + (4 * wave + n) * 16 + lr]
                                       : b_time[(4 * wave + n) * 16 + lr];
#pragma unroll
                for (int mm = 0; mm < 2; ++mm) {
                    int m = 2 * mh + mm;
#pragma unroll
                    for (int r = 0; r < 4; ++r) {
                        if (pass == 0) accY[m][n][r] *= (1.0f + bt + acc2[mm][n][r]);
                        else           accY[m][n][r] += bt + acc2[mm][n][r];
                    }
                }
            }
        }
    }

    // write U (bf16) into sU (sX region dead)
#pragma unroll
    for (int m = 0; m < 4; ++m) {
#pragma unroll
        for (int r = 0; r < 4; ++r) {
            int e = m * 16 + lq * 4 + r;
#pragma unroll
            for (int n = 0; n < 4; ++n)
                sU[e][(4 * wave + n) * 16 + lr] = __float2bfloat16(accY[m][n][r]);
        }
    }
    __syncthreads();

    // ---- Phase Z: Z = U @ W_c1 (barrier-free inner loop) ----
    f32x4 accZ[4][4];
#pragma unroll
    for (int m = 0; m < 4; ++m)
#pragma unroll
        for (int n = 0; n < 4; ++n) accZ[m][n] = (f32x4){0.f, 0.f, 0.f, 0.f};

#pragma unroll
    for (int kt = 0; kt < 8; ++kt) {
        bf16x8 afr[4];
#pragma unroll
        for (int m = 0; m < 4; ++m)
            afr[m] = *reinterpret_cast<const bf16x8*>(&sU[m * 16 + lr][kt * 32 + lq * 8]);
#pragma unroll
        for (int n = 0; n < 4; ++n) {
            bf16x8 bfr = *reinterpret_cast<const bf16x8*>(
                pWc1 + ((size_t)(kt * 16 + 4 * wave + n) * 64 + lane) * 8);
#pragma unroll
            for (int m = 0; m < 4; ++m)
                accZ[m][n] = __builtin_amdgcn_mfma_f32_16x16x32_bf16(afr[m], bfr, accZ[m][n], 0, 0, 0);
        }
    }

    // s = silu(Z + b_c1) @ W_c2 (per-edge scalar)
#pragma unroll
    for (int m = 0; m < 4; ++m) {
        float ps0 = 0.f, ps1 = 0.f, ps2 = 0.f, ps3 = 0.f;
#pragma unroll
        for (int n = 0; n < 4; ++n) {
            int colg = (4 * wave + n) * 16 + lr;
            float bc = b_c1[colg];
            float w2 = W_c2[colg];
            ps0 += silu_f(accZ[m][n][0] + bc) * w2;
            ps1 += silu_f(accZ[m][n][1] + bc) * w2;
            ps2 += silu_f(accZ[m][n][2] + bc) * w2;
            ps3 += silu_f(accZ[m][n][3] + bc) * w2;
        }
        float ps[4] = {ps0, ps1, ps2, ps3};
#pragma unroll
        for (int r = 0; r < 4; ++r) {
            float v = ps[r];
#pragma unroll
            for (int off = 1; off < 16; off <<= 1) v += __shfl_xor(v, off, 64);
            if (lr == 0) atomicAdd(&sS[m * 16 + lq * 4 + r], v);
        }
    }
    __syncthreads();

    // ---- epilogue: coord update + segment-sum atomics ----
    if (tid < 64) {
        int e = tid;
        float inv = tanhf(sS[e]);
        int rI = sRow[e], cI = sCol[e];
        float dx = pos[rI * 3 + 0] - pos[cI * 3 + 0];
        float dy = pos[rI * 3 + 1] - pos[cI * 3 + 1];
        float dz = pos[rI * 3 + 2] - pos[cI * 3 + 2];
        float nrm = sqrtf(dx * dx + dy * dy + dz * dz);
        float f = coord_scale[0] * inv / fmaxf(nrm, 1e-8f);
        atomicAdd(&out[rI * 3 + 0], dx * f);
        atomicAdd(&out[rI * 3 + 1], dy * f);
        atomicAdd(&out[rI * 3 + 2], dz * f);
    }
}

extern "C" void kernel_launch(void* const* d_in, const int* in_sizes, int n_in,
                              void* d_out, int out_size, void* d_ws, size_t ws_size,
                              hipStream_t stream) {
    const float* h          = (const float*)d_in[0];
    const float* pos        = (const float*)d_in[1];
    const float* edge_attr  = (const float*)d_in[2];
    const float* dist       = (const float*)d_in[3];
    const float* time_emb   = (const float*)d_in[4];
    const int*   edge_index = (const int*)d_in[5];
    const float* W_time     = (const float*)d_in[6];
    const float* b_time     = (const float*)d_in[7];
    const float* W_in       = (const float*)d_in[8];
    const float* b_in       = (const float*)d_in[9];
    const float* W_c1       = (const float*)d_in[10];
    const float* b_c1       = (const float*)d_in[11];
    const float* W_c2       = (const float*)d_in[12];
    const float* coord_scale= (const float*)d_in[13];
    float* out = (float*)d_out;

    unsigned short* pWin   = (unsigned short*)d_ws;                       // 704*256*2 = 360448 B
    unsigned short* pWtime = (unsigned short*)((char*)d_ws + 360448);     // 256*512*2 = 262144 B
    unsigned short* pWc1   = (unsigned short*)((char*)d_ws + 622592);     // 256*256*2 = 131072 B

    pack_weights<<<88, 256, 0, stream>>>(W_in,   pWin,   INCH, HID);
    pack_weights<<<64, 256, 0, stream>>>(W_time, pWtime, TDIM, 2 * HID);
    pack_weights<<<32, 256, 0, stream>>>(W_c1,   pWc1,   HID,  HID);
    init_out<<<(3 * NN + 255) / 256, 256, 0, stream>>>(pos, out, 3 * NN);

    edge_kernel<<<NE / 64, 256, 0, stream>>>(
        h, pos, edge_attr, dist, time_emb, edge_index,
        b_time, b_in, b_c1, W_c2, coord_scale,
        pWtime, pWin, pWc1, out);
}

// Round 6
// 725.628 us; speedup vs baseline: 1.8315x; 1.0629x over previous
//
#include <hip/hip_runtime.h>
#include <hip/hip_bf16.h>

#define NN   20000
#define NE   320000
#define HID  256
#define EDIM 128
#define DDIM 64
#define TDIM 256
#define INCH 704

typedef __attribute__((ext_vector_type(8))) short bf16x8;
typedef __attribute__((ext_vector_type(4))) float f32x4;
typedef __attribute__((ext_vector_type(4))) unsigned int u32x4;

__device__ __forceinline__ unsigned short f2bu(float x) {
    return __bfloat16_as_ushort(__float2bfloat16(x));
}
__device__ __forceinline__ unsigned pk2(float lo, float hi) {
    return (unsigned)f2bu(lo) | ((unsigned)f2bu(hi) << 16);
}
__device__ __forceinline__ float silu_f(float x) {
    return x / (1.0f + __expf(-x));
}

// Pack fp32 [K][Nc] row-major weight into bf16 MFMA B-fragment order:
// frag element j of lane l of tile (kt,nt) = B[kt*32 + (l>>4)*8 + j][nt*16 + (l&15)]
// stored at dst[((kt*NT+nt)*64 + l)*8 + j]. A staging uses the same (l>>4, j)->k
// mapping, so any HW within-K-tile permutation cancels.
__global__ void pack_weights(const float* __restrict__ src, unsigned short* __restrict__ dst,
                             int K, int Nc) {
    int KT = K >> 5, NT = Nc >> 4;
    int total = KT * NT * 64;
    int idx = blockIdx.x * blockDim.x + threadIdx.x;
    if (idx >= total) return;
    int lane = idx & 63;
    int tile = idx >> 6;
    int nt = tile % NT, kt = tile / NT;
    int n = nt * 16 + (lane & 15);
    int k0 = kt * 32 + (lane >> 4) * 8;
    alignas(16) unsigned short v[8];
#pragma unroll
    for (int j = 0; j < 8; ++j) v[j] = f2bu(src[(size_t)(k0 + j) * Nc + n]);
    *reinterpret_cast<u32x4*>(dst + (size_t)idx * 8) = *reinterpret_cast<const u32x4*>(v);
}

__global__ void init_out(const float* __restrict__ pos, float* __restrict__ out, int n) {
    int i = blockIdx.x * blockDim.x + threadIdx.x;
    if (i < n) out[i] = pos[i];
}

__global__ __launch_bounds__(512, 2) void edge_kernel(
    const float* __restrict__ h, const float* __restrict__ pos,
    const float* __restrict__ edge_attr, const float* __restrict__ dist,
    const float* __restrict__ time_emb, const int* __restrict__ edge_index,
    const float* __restrict__ b_time, const float* __restrict__ b_in,
    const float* __restrict__ b_c1, const float* __restrict__ W_c2,
    const float* __restrict__ coord_scale,
    const unsigned short* __restrict__ pWtime, const unsigned short* __restrict__ pWin,
    const unsigned short* __restrict__ pWc1,
    float* __restrict__ out)
{
    // 8 waves per block, 64 edges per block. Each wave owns a 64x32 output slice
    // (n-tiles 2*wave, 2*wave+1) -> accY[4][2] = 32 acc regs per lane.
    // Region 1 (persistent): sT[64][264] = silu(time_emb) bf16.
    // Region 2 (time-muxed): sX[2][64][72] double-buffered Y A-chunks, then sU[64][264].
    __shared__ __align__(16) unsigned char smemT[64 * 264 * 2];
    __shared__ __align__(16) unsigned char smem2[64 * 264 * 2];
    __hip_bfloat16 (*sT)[264]    = reinterpret_cast<__hip_bfloat16(*)[264]>(smemT);
    __hip_bfloat16 (*sU)[264]    = reinterpret_cast<__hip_bfloat16(*)[264]>(smem2);
    __hip_bfloat16 (*sX)[64][72] = reinterpret_cast<__hip_bfloat16(*)[64][72]>(smem2);
    __shared__ float sSum[64], sSq[64], sS[64];
    __shared__ int sRow[64], sCol[64];

    const int tid = threadIdx.x;
    const int wave = tid >> 6, lane = tid & 63;
    const int lq = lane >> 4, lr = lane & 15;
    const int e0 = blockIdx.x * 64;
    const int el = tid >> 3, part = tid & 7;   // staging: 64 edges x 8 parts (8 floats each)

    // direct index loads so the h-gather prefetch can issue immediately
    const int rIdx = edge_index[e0 + el];
    const int cIdx = edge_index[NE + e0 + el];

    // prefetch Y chunk 0 (h[rIdx] cols 0..63, this thread's 8) — hides under sT staging
    float rY[8];
    {
        const float* p = h + (size_t)rIdx * HID + part * 8;
        *reinterpret_cast<float4*>(&rY[0]) = *reinterpret_cast<const float4*>(p);
        *reinterpret_cast<float4*>(&rY[4]) = *reinterpret_cast<const float4*>(p + 4);
    }

    if (tid < 64) {
        sRow[tid] = edge_index[e0 + tid];
        sCol[tid] = edge_index[NE + e0 + tid];
        sSum[tid] = 0.f; sSq[tid] = 0.f; sS[tid] = 0.f;
    }

    // ---- stage silu(time_emb) into sT (bf16), once: 32 floats/thread ----
    {
        const float* p = time_emb + (size_t)(e0 + el) * TDIM + part * 32;
#pragma unroll
        for (int j = 0; j < 4; ++j) {
            float4 a = *reinterpret_cast<const float4*>(p + j * 8);
            float4 b = *reinterpret_cast<const float4*>(p + j * 8 + 4);
            u32x4 w;
            w.x = pk2(silu_f(a.x), silu_f(a.y)); w.y = pk2(silu_f(a.z), silu_f(a.w));
            w.z = pk2(silu_f(b.x), silu_f(b.y)); w.w = pk2(silu_f(b.z), silu_f(b.w));
            *reinterpret_cast<u32x4*>(&sT[el][part * 32 + j * 8]) = w;
        }
    }

    // write prefetched chunk 0 into sX[0]
    {
        u32x4 w;
        w.x = pk2(rY[0], rY[1]); w.y = pk2(rY[2], rY[3]);
        w.z = pk2(rY[4], rY[5]); w.w = pk2(rY[6], rY[7]);
        *reinterpret_cast<u32x4*>(&sX[0][el][part * 8]) = w;
    }
    __syncthreads();   // B1: sT, sX[0], sRow/sCol, zeroed stats ready

    // ---- Phase Y: Y = [h[row]|h[col]|ea|dist] @ W_in, BK=64, reg-staged pipeline ----
    f32x4 accY[4][2];
#pragma unroll
    for (int m = 0; m < 4; ++m)
#pragma unroll
        for (int n = 0; n < 2; ++n) accY[m][n] = (f32x4){0.f, 0.f, 0.f, 0.f};

#pragma unroll 2
    for (int kt = 0; kt < 11; ++kt) {
        const int buf = kt & 1;
        // (1) issue next chunk's global loads early (regs)
        if (kt < 10) {
            const int kn = kt + 1;
            const float* p;
            if (kn < 4)       p = h + (size_t)rIdx * HID + kn * 64;
            else if (kn < 8)  p = h + (size_t)cIdx * HID + (kn - 4) * 64;
            else if (kn < 10) p = edge_attr + (size_t)(e0 + el) * EDIM + (kn - 8) * 64;
            else              p = dist + (size_t)(e0 + el) * DDIM;
            p += part * 8;
            *reinterpret_cast<float4*>(&rY[0]) = *reinterpret_cast<const float4*>(p);
            *reinterpret_cast<float4*>(&rY[4]) = *reinterpret_cast<const float4*>(p + 4);
        }
        // (2) ds_read current buffer + MFMA
#pragma unroll
        for (int kq = 0; kq < 2; ++kq) {
            bf16x8 afr[4];
#pragma unroll
            for (int m = 0; m < 4; ++m)
                afr[m] = *reinterpret_cast<const bf16x8*>(&sX[buf][m * 16 + lr][kq * 32 + lq * 8]);
#pragma unroll
            for (int n = 0; n < 2; ++n) {
                bf16x8 bfr = *reinterpret_cast<const bf16x8*>(
                    pWin + ((size_t)((2 * kt + kq) * 16 + 2 * wave + n) * 64 + lane) * 8);
#pragma unroll
                for (int m = 0; m < 4; ++m)
                    accY[m][n] = __builtin_amdgcn_mfma_f32_16x16x32_bf16(afr[m], bfr, accY[m][n], 0, 0, 0);
            }
        }
        // (3) convert + write next buffer late
        if (kt < 10) {
            u32x4 w;
            w.x = pk2(rY[0], rY[1]); w.y = pk2(rY[2], rY[3]);
            w.z = pk2(rY[4], rY[5]); w.w = pk2(rY[6], rY[7]);
            *reinterpret_cast<u32x4*>(&sX[buf ^ 1][el][part * 8]) = w;
        }
        __syncthreads();
    }
    // sX region dead after final barrier

    // + b_in
#pragma unroll
    for (int n = 0; n < 2; ++n) {
        float bi = b_in[(2 * wave + n) * 16 + lr];
#pragma unroll
        for (int m = 0; m < 4; ++m) {
            accY[m][n].x += bi; accY[m][n].y += bi; accY[m][n].z += bi; accY[m][n].w += bi;
        }
    }

    // LayerNorm stats across 256 cols (8 waves x 32 cols each)
#pragma unroll
    for (int m = 0; m < 4; ++m) {
#pragma unroll
        for (int r = 0; r < 4; ++r) {
            float v0 = accY[m][0][r], v1 = accY[m][1][r];
            float s1 = v0 + v1;
            float s2 = v0 * v0 + v1 * v1;
#pragma unroll
            for (int off = 1; off < 16; off <<= 1) {
                s1 += __shfl_xor(s1, off, 64);
                s2 += __shfl_xor(s2, off, 64);
            }
            if (lr == 0) {
                atomicAdd(&sSum[m * 16 + lq * 4 + r], s1);
                atomicAdd(&sSq[m * 16 + lq * 4 + r], s2);
            }
        }
    }
    __syncthreads();

    // normalize in place: accY <- LN(Y)
#pragma unroll
    for (int m = 0; m < 4; ++m) {
#pragma unroll
        for (int r = 0; r < 4; ++r) {
            int e = m * 16 + lq * 4 + r;
            float mu = sSum[e] * (1.0f / 256.0f);
            float var = sSq[e] * (1.0f / 256.0f) - mu * mu;
            float rs = rsqrtf(var + 1e-6f);
#pragma unroll
            for (int n = 0; n < 2; ++n)
                accY[m][n][r] = (accY[m][n][r] - mu) * rs;
        }
    }

    // ---- Phase T: FiLM via two passes (scale, shift), m-split halves (acc2 = 16 regs) ----
#pragma unroll
    for (int pass = 0; pass < 2; ++pass) {
#pragma unroll
        for (int mh = 0; mh < 2; ++mh) {
            f32x4 acc2[2][2];
#pragma unroll
            for (int mm = 0; mm < 2; ++mm)
#pragma unroll
                for (int n = 0; n < 2; ++n) acc2[mm][n] = (f32x4){0.f, 0.f, 0.f, 0.f};
#pragma unroll
            for (int kt = 0; kt < 8; ++kt) {
                bf16x8 afr[2];
#pragma unroll
                for (int mm = 0; mm < 2; ++mm)
                    afr[mm] = *reinterpret_cast<const bf16x8*>(
                        &sT[(2 * mh + mm) * 16 + lr][kt * 32 + lq * 8]);
#pragma unroll
                for (int n = 0; n < 2; ++n) {
                    int ncol = (pass == 0) ? (16 + 2 * wave + n) : (2 * wave + n);
                    bf16x8 bfr = *reinterpret_cast<const bf16x8*>(
                        pWtime + ((size_t)(kt * 32 + ncol) * 64 + lane) * 8);
#pragma unroll
                    for (int mm = 0; mm < 2; ++mm)
                        acc2[mm][n] = __builtin_amdgcn_mfma_f32_16x16x32_bf16(afr[mm], bfr, acc2[mm][n], 0, 0, 0);
                }
            }
#pragma unroll
            for (int n = 0; n < 2; ++n) {
                float bt = (pass == 0) ? b_time[256 + (2 * wave + n) * 16 + lr]
                                       : b_time[(2 * wave + n) * 16 + lr];
#pragma unroll
                for (int mm = 0; mm < 2; ++mm) {
                    int m = 2 * mh + mm;
#pragma unroll
                    for (int r = 0; r < 4; ++r) {
                        if (pass == 0) accY[m][n][r] *= (1.0f + bt + acc2[mm][n][r]);
                        else           accY[m][n][r] += bt + acc2[mm][n][r];
                    }
                }
            }
        }
    }

    // write U (bf16) into sU (sX region dead)
#pragma unroll
    for (int m = 0; m < 4; ++m) {
#pragma unroll
        for (int r = 0; r < 4; ++r) {
            int e = m * 16 + lq * 4 + r;
#pragma unroll
            for (int n = 0; n < 2; ++n)
                sU[e][(2 * wave + n) * 16 + lr] = __float2bfloat16(accY[m][n][r]);
        }
    }
    __syncthreads();

    // ---- Phase Z: Z = U @ W_c1 (barrier-free inner loop) ----
    f32x4 accZ[4][2];
#pragma unroll
    for (int m = 0; m < 4; ++m)
#pragma unroll
        for (int n = 0; n < 2; ++n) accZ[m][n] = (f32x4){0.f, 0.f, 0.f, 0.f};

#pragma unroll
    for (int kt = 0; kt < 8; ++kt) {
        bf16x8 afr[4];
#pragma unroll
        for (int m = 0; m < 4; ++m)
            afr[m] = *reinterpret_cast<const bf16x8*>(&sU[m * 16 + lr][kt * 32 + lq * 8]);
#pragma unroll
        for (int n = 0; n < 2; ++n) {
            bf16x8 bfr = *reinterpret_cast<const bf16x8*>(
                pWc1 + ((size_t)(kt * 16 + 2 * wave + n) * 64 + lane) * 8);
#pragma unroll
            for (int m = 0; m < 4; ++m)
                accZ[m][n] = __builtin_amdgcn_mfma_f32_16x16x32_bf16(afr[m], bfr, accZ[m][n], 0, 0, 0);
        }
    }

    // s = silu(Z + b_c1) @ W_c2 (per-edge scalar)
#pragma unroll
    for (int m = 0; m < 4; ++m) {
        float ps0 = 0.f, ps1 = 0.f, ps2 = 0.f, ps3 = 0.f;
#pragma unroll
        for (int n = 0; n < 2; ++n) {
            int colg = (2 * wave + n) * 16 + lr;
            float bc = b_c1[colg];
            float w2 = W_c2[colg];
            ps0 += silu_f(accZ[m][n][0] + bc) * w2;
            ps1 += silu_f(accZ[m][n][1] + bc) * w2;
            ps2 += silu_f(accZ[m][n][2] + bc) * w2;
            ps3 += silu_f(accZ[m][n][3] + bc) * w2;
        }
        float ps[4] = {ps0, ps1, ps2, ps3};
#pragma unroll
        for (int r = 0; r < 4; ++r) {
            float v = ps[r];
#pragma unroll
            for (int off = 1; off < 16; off <<= 1) v += __shfl_xor(v, off, 64);
            if (lr == 0) atomicAdd(&sS[m * 16 + lq * 4 + r], v);
        }
    }
    __syncthreads();

    // ---- epilogue: coord update + segment-sum atomics ----
    if (tid < 64) {
        int e = tid;
        float inv = tanhf(sS[e]);
        int rI = sRow[e], cI = sCol[e];
        float dx = pos[rI * 3 + 0] - pos[cI * 3 + 0];
        float dy = pos[rI * 3 + 1] - pos[cI * 3 + 1];
        float dz = pos[rI * 3 + 2] - pos[cI * 3 + 2];
        float nrm = sqrtf(dx * dx + dy * dy + dz * dz);
        float f = coord_scale[0] * inv / fmaxf(nrm, 1e-8f);
        atomicAdd(&out[rI * 3 + 0], dx * f);
        atomicAdd(&out[rI * 3 + 1], dy * f);
        atomicAdd(&out[rI * 3 + 2], dz * f);
    }
}

extern "C" void kernel_launch(void* const* d_in, const int* in_sizes, int n_in,
                              void* d_out, int out_size, void* d_ws, size_t ws_size,
                              hipStream_t stream) {
    const float* h          = (const float*)d_in[0];
    const float* pos        = (const float*)d_in[1];
    const float* edge_attr  = (const float*)d_in[2];
    const float* dist       = (const float*)d_in[3];
    const float* time_emb   = (const float*)d_in[4];
    const int*   edge_index = (const int*)d_in[5];
    const float* W_time     = (const float*)d_in[6];
    const float* b_time     = (const float*)d_in[7];
    const float* W_in       = (const float*)d_in[8];
    const float* b_in       = (const float*)d_in[9];
    const float* W_c1       = (const float*)d_in[10];
    const float* b_c1       = (const float*)d_in[11];
    const float* W_c2       = (const float*)d_in[12];
    const float* coord_scale= (const float*)d_in[13];
    float* out = (float*)d_out;

    unsigned short* pWin   = (unsigned short*)d_ws;                       // 704*256*2 = 360448 B
    unsigned short* pWtime = (unsigned short*)((char*)d_ws + 360448);     // 256*512*2 = 262144 B
    unsigned short* pWc1   = (unsigned short*)((char*)d_ws + 622592);     // 256*256*2 = 131072 B

    pack_weights<<<88, 256, 0, stream>>>(W_in,   pWin,   INCH, HID);
    pack_weights<<<64, 256, 0, stream>>>(W_time, pWtime, TDIM, 2 * HID);
    pack_weights<<<32, 256, 0, stream>>>(W_c1,   pWc1,   HID,  HID);
    init_out<<<(3 * NN + 255) / 256, 256, 0, stream>>>(pos, out, 3 * NN);

    edge_kernel<<<NE / 64, 512, 0, stream>>>(
        h, pos, edge_attr, dist, time_emb, edge_index,
        b_time, b_in, b_c1, W_c2, coord_scale,
        pWtime, pWin, pWc1, out);
}

// Round 7
// 643.064 us; speedup vs baseline: 2.0667x; 1.1284x over previous
//
#include <hip/hip_runtime.h>
#include <hip/hip_bf16.h>

#define NN   20000
#define NE   320000
#define HID  256
#define EDIM 128
#define DDIM 64
#define TDIM 256
#define INCH 704

typedef __attribute__((ext_vector_type(8))) short bf16x8;
typedef __attribute__((ext_vector_type(4))) float f32x4;
typedef __attribute__((ext_vector_type(4))) unsigned int u32x4;

__device__ __forceinline__ unsigned short f2bu(float x) {
    return __bfloat16_as_ushort(__float2bfloat16(x));
}
__device__ __forceinline__ unsigned pk2(float lo, float hi) {
    return (unsigned)f2bu(lo) | ((unsigned)f2bu(hi) << 16);
}
__device__ __forceinline__ float silu_f(float x) {
    return x / (1.0f + __expf(-x));
}

// Pack fp32 [K][Nc] row-major weight into bf16 MFMA B-fragment order:
// frag element j of lane l of tile (kt,nt) = B[kt*32 + (l>>4)*8 + j][nt*16 + (l&15)]
// stored at dst[((kt*NT+nt)*64 + l)*8 + j]. A staging uses the same (l>>4, j)->k
// mapping, so any HW within-K-tile permutation cancels.
__global__ void pack_weights(const float* __restrict__ src, unsigned short* __restrict__ dst,
                             int K, int Nc) {
    int KT = K >> 5, NT = Nc >> 4;
    int total = KT * NT * 64;
    int idx = blockIdx.x * blockDim.x + threadIdx.x;
    if (idx >= total) return;
    int lane = idx & 63;
    int tile = idx >> 6;
    int nt = tile % NT, kt = tile / NT;
    int n = nt * 16 + (lane & 15);
    int k0 = kt * 32 + (lane >> 4) * 8;
    alignas(16) unsigned short v[8];
#pragma unroll
    for (int j = 0; j < 8; ++j) v[j] = f2bu(src[(size_t)(k0 + j) * Nc + n]);
    *reinterpret_cast<u32x4*>(dst + (size_t)idx * 8) = *reinterpret_cast<const u32x4*>(v);
}

__global__ void init_out(const float* __restrict__ pos, float* __restrict__ out, int n) {
    int i = blockIdx.x * blockDim.x + threadIdx.x;
    if (i < n) out[i] = pos[i];
}

__global__ __launch_bounds__(512, 4) void edge_kernel(
    const float* __restrict__ h, const float* __restrict__ pos,
    const float* __restrict__ edge_attr, const float* __restrict__ dist,
    const float* __restrict__ time_emb, const int* __restrict__ edge_index,
    const float* __restrict__ b_time, const float* __restrict__ b_in,
    const float* __restrict__ b_c1, const float* __restrict__ W_c2,
    const float* __restrict__ coord_scale,
    const unsigned short* __restrict__ pWtime, const unsigned short* __restrict__ pWin,
    const unsigned short* __restrict__ pWc1,
    float* __restrict__ out)
{
    // 8 waves per block, 64 edges per block. Each wave owns a 64x32 output slice
    // (n-tiles 2*wave, 2*wave+1) -> accY[4][2] = 32 acc regs per lane.
    // launch_bounds(512,4): cap 128 unified regs/wave -> 2 blocks/CU (16 waves).
    // Region 1 (persistent): sT[64][264] = silu(time_emb) bf16.
    // Region 2 (time-muxed): sX[2][64][72] double-buffered Y A-chunks, then sU[64][264].
    __shared__ __align__(16) unsigned char smemT[64 * 264 * 2];
    __shared__ __align__(16) unsigned char smem2[64 * 264 * 2];
    __hip_bfloat16 (*sT)[264]    = reinterpret_cast<__hip_bfloat16(*)[264]>(smemT);
    __hip_bfloat16 (*sU)[264]    = reinterpret_cast<__hip_bfloat16(*)[264]>(smem2);
    __hip_bfloat16 (*sX)[64][72] = reinterpret_cast<__hip_bfloat16(*)[64][72]>(smem2);
    __shared__ float sSum[64], sSq[64], sS[64];
    __shared__ int sRow[64], sCol[64];

    const int tid = threadIdx.x;
    const int wave = tid >> 6, lane = tid & 63;
    const int lq = lane >> 4, lr = lane & 15;
    const int e0 = blockIdx.x * 64;
    const int el = tid >> 3, part = tid & 7;   // staging: 64 edges x 8 parts (8 floats each)

    // direct index loads so the h-gather prefetch can issue immediately
    const int rIdx = edge_index[e0 + el];
    const int cIdx = edge_index[NE + e0 + el];

    // chunk address helper: chunk kn covers X cols [kn*64, kn*64+64)
    auto chunk_ptr = [&](int kn) -> const float* {
        const float* p;
        if (kn < 4)       p = h + (size_t)rIdx * HID + kn * 64;
        else if (kn < 8)  p = h + (size_t)cIdx * HID + (kn - 4) * 64;
        else if (kn < 10) p = edge_attr + (size_t)(e0 + el) * EDIM + (kn - 8) * 64;
        else              p = dist + (size_t)(e0 + el) * DDIM;
        return p + part * 8;
    };

    // prefetch chunk 0 (-> sX[0] before B1) and chunk 1 (stays in rA) up front;
    // latency hides under the sT staging VALU work.
    float r0[8], rA[8], rB[8];
    {
        const float* p = chunk_ptr(0);
        *reinterpret_cast<float4*>(&r0[0]) = *reinterpret_cast<const float4*>(p);
        *reinterpret_cast<float4*>(&r0[4]) = *reinterpret_cast<const float4*>(p + 4);
        const float* q = chunk_ptr(1);
        *reinterpret_cast<float4*>(&rA[0]) = *reinterpret_cast<const float4*>(q);
        *reinterpret_cast<float4*>(&rA[4]) = *reinterpret_cast<const float4*>(q + 4);
    }

    if (tid < 64) {
        sRow[tid] = edge_index[e0 + tid];
        sCol[tid] = edge_index[NE + e0 + tid];
        sSum[tid] = 0.f; sSq[tid] = 0.f; sS[tid] = 0.f;
    }

    // ---- stage silu(time_emb) into sT (bf16), once: 32 floats/thread ----
    {
        const float* p = time_emb + (size_t)(e0 + el) * TDIM + part * 32;
#pragma unroll
        for (int j = 0; j < 4; ++j) {
            float4 a = *reinterpret_cast<const float4*>(p + j * 8);
            float4 b = *reinterpret_cast<const float4*>(p + j * 8 + 4);
            u32x4 w;
            w.x = pk2(silu_f(a.x), silu_f(a.y)); w.y = pk2(silu_f(a.z), silu_f(a.w));
            w.z = pk2(silu_f(b.x), silu_f(b.y)); w.w = pk2(silu_f(b.z), silu_f(b.w));
            *reinterpret_cast<u32x4*>(&sT[el][part * 32 + j * 8]) = w;
        }
    }

    // write prefetched chunk 0 into sX[0]
    {
        u32x4 w;
        w.x = pk2(r0[0], r0[1]); w.y = pk2(r0[2], r0[3]);
        w.z = pk2(r0[4], r0[5]); w.w = pk2(r0[6], r0[7]);
        *reinterpret_cast<u32x4*>(&sX[0][el][part * 8]) = w;
    }
    __syncthreads();   // B1: sT, sX[0], sRow/sCol, zeroed stats ready

    // ---- Phase Y: Y = [h[row]|h[col]|ea|dist] @ W_in, BK=64, depth-2 prefetch ----
    // iter kt: load chunk kt+2 -> rB ; MFMA on sX[kt&1] (chunk kt) ;
    //          write rA (chunk kt+1, arrived ~1 full iter ago) -> sX[(kt&1)^1] ; rA <- rB
    f32x4 accY[4][2];
#pragma unroll
    for (int m = 0; m < 4; ++m)
#pragma unroll
        for (int n = 0; n < 2; ++n) accY[m][n] = (f32x4){0.f, 0.f, 0.f, 0.f};

#pragma unroll 2
    for (int kt = 0; kt < 11; ++kt) {
        const int buf = kt & 1;
        // (1) issue chunk kt+2's global loads (depth-2)
        if (kt < 9) {
            const float* p = chunk_ptr(kt + 2);
            *reinterpret_cast<float4*>(&rB[0]) = *reinterpret_cast<const float4*>(p);
            *reinterpret_cast<float4*>(&rB[4]) = *reinterpret_cast<const float4*>(p + 4);
        }
        // (2) ds_read current buffer + MFMA
#pragma unroll
        for (int kq = 0; kq < 2; ++kq) {
            bf16x8 afr[4];
#pragma unroll
            for (int m = 0; m < 4; ++m)
                afr[m] = *reinterpret_cast<const bf16x8*>(&sX[buf][m * 16 + lr][kq * 32 + lq * 8]);
#pragma unroll
            for (int n = 0; n < 2; ++n) {
                bf16x8 bfr = *reinterpret_cast<const bf16x8*>(
                    pWin + ((size_t)((2 * kt + kq) * 16 + 2 * wave + n) * 64 + lane) * 8);
#pragma unroll
                for (int m = 0; m < 4; ++m)
                    accY[m][n] = __builtin_amdgcn_mfma_f32_16x16x32_bf16(afr[m], bfr, accY[m][n], 0, 0, 0);
            }
        }
        // (3) convert + write chunk kt+1 (in rA) to the other buffer
        if (kt < 10) {
            u32x4 w;
            w.x = pk2(rA[0], rA[1]); w.y = pk2(rA[2], rA[3]);
            w.z = pk2(rA[4], rA[5]); w.w = pk2(rA[6], rA[7]);
            *reinterpret_cast<u32x4*>(&sX[buf ^ 1][el][part * 8]) = w;
        }
        // (4) rotate prefetch regs (static under unroll-2)
        if (kt < 9) {
#pragma unroll
            for (int j = 0; j < 8; ++j) rA[j] = rB[j];
        }
        __syncthreads();
    }
    // sX region dead after final barrier

    // + b_in
#pragma unroll
    for (int n = 0; n < 2; ++n) {
        float bi = b_in[(2 * wave + n) * 16 + lr];
#pragma unroll
        for (int m = 0; m < 4; ++m) {
            accY[m][n].x += bi; accY[m][n].y += bi; accY[m][n].z += bi; accY[m][n].w += bi;
        }
    }

    // LayerNorm stats across 256 cols (8 waves x 32 cols each)
#pragma unroll
    for (int m = 0; m < 4; ++m) {
#pragma unroll
        for (int r = 0; r < 4; ++r) {
            float v0 = accY[m][0][r], v1 = accY[m][1][r];
            float s1 = v0 + v1;
            float s2 = v0 * v0 + v1 * v1;
#pragma unroll
            for (int off = 1; off < 16; off <<= 1) {
                s1 += __shfl_xor(s1, off, 64);
                s2 += __shfl_xor(s2, off, 64);
            }
            if (lr == 0) {
                atomicAdd(&sSum[m * 16 + lq * 4 + r], s1);
                atomicAdd(&sSq[m * 16 + lq * 4 + r], s2);
            }
        }
    }
    __syncthreads();

    // normalize in place: accY <- LN(Y)
#pragma unroll
    for (int m = 0; m < 4; ++m) {
#pragma unroll
        for (int r = 0; r < 4; ++r) {
            int e = m * 16 + lq * 4 + r;
            float mu = sSum[e] * (1.0f / 256.0f);
            float var = sSq[e] * (1.0f / 256.0f) - mu * mu;
            float rs = rsqrtf(var + 1e-6f);
#pragma unroll
            for (int n = 0; n < 2; ++n)
                accY[m][n][r] = (accY[m][n][r] - mu) * rs;
        }
    }

    // ---- Phase T: FiLM via two passes (scale, shift), m-split halves (acc2 = 16 regs) ----
#pragma unroll
    for (int pass = 0; pass < 2; ++pass) {
#pragma unroll
        for (int mh = 0; mh < 2; ++mh) {
            f32x4 acc2[2][2];
#pragma unroll
            for (int mm = 0; mm < 2; ++mm)
#pragma unroll
                for (int n = 0; n < 2; ++n) acc2[mm][n] = (f32x4){0.f, 0.f, 0.f, 0.f};
#pragma unroll
            for (int kt = 0; kt < 8; ++kt) {
                bf16x8 afr[2];
#pragma unroll
                for (int mm = 0; mm < 2; ++mm)
                    afr[mm] = *reinterpret_cast<const bf16x8*>(
                        &sT[(2 * mh + mm) * 16 + lr][kt * 32 + lq * 8]);
#pragma unroll
                for (int n = 0; n < 2; ++n) {
                    int ncol = (pass == 0) ? (16 + 2 * wave + n) : (2 * wave + n);
                    bf16x8 bfr = *reinterpret_cast<const bf16x8*>(
                        pWtime + ((size_t)(kt * 32 + ncol) * 64 + lane) * 8);
#pragma unroll
                    for (int mm = 0; mm < 2; ++mm)
                        acc2[mm][n] = __builtin_amdgcn_mfma_f32_16x16x32_bf16(afr[mm], bfr, acc2[mm][n], 0, 0, 0);
                }
            }
#pragma unroll
            for (int n = 0; n < 2; ++n) {
                float bt = (pass == 0) ? b_time[256 + (2 * wave + n) * 16 + lr]
                                       : b_time[(2 * wave + n) * 16 + lr];
#pragma unroll
                for (int mm = 0; mm < 2; ++mm) {
                    int m = 2 * mh + mm;
#pragma unroll
                    for (int r = 0; r < 4; ++r) {
                        if (pass == 0) accY[m][n][r] *= (1.0f + bt + acc2[mm][n][r]);
                        else           accY[m][n][r] += bt + acc2[mm][n][r];
                    }
                }
            }
        }
    }

    // write U (bf16) into sU (sX region dead)
#pragma unroll
    for (int m = 0; m < 4; ++m) {
#pragma unroll
        for (int r = 0; r < 4; ++r) {
            int e = m * 16 + lq * 4 + r;
#pragma unroll
            for (int n = 0; n < 2; ++n)
                sU[e][(2 * wave + n) * 16 + lr] = __float2bfloat16(accY[m][n][r]);
        }
    }
    __syncthreads();

    // ---- Phase Z: Z = U @ W_c1 (barrier-free inner loop) ----
    f32x4 accZ[4][2];
#pragma unroll
    for (int m = 0; m < 4; ++m)
#pragma unroll
        for (int n = 0; n < 2; ++n) accZ[m][n] = (f32x4){0.f, 0.f, 0.f, 0.f};

#pragma unroll
    for (int kt = 0; kt < 8; ++kt) {
        bf16x8 afr[4];
#pragma unroll
        for (int m = 0; m < 4; ++m)
            afr[m] = *reinterpret_cast<const bf16x8*>(&sU[m * 16 + lr][kt * 32 + lq * 8]);
#pragma unroll
        for (int n = 0; n < 2; ++n) {
            bf16x8 bfr = *reinterpret_cast<const bf16x8*>(
                pWc1 + ((size_t)(kt * 16 + 2 * wave + n) * 64 + lane) * 8);
#pragma unroll
            for (int m = 0; m < 4; ++m)
                accZ[m][n] = __builtin_amdgcn_mfma_f32_16x16x32_bf16(afr[m], bfr, accZ[m][n], 0, 0, 0);
        }
    }

    // s = silu(Z + b_c1) @ W_c2 (per-edge scalar)
#pragma unroll
    for (int m = 0; m < 4; ++m) {
        float ps0 = 0.f, ps1 = 0.f, ps2 = 0.f, ps3 = 0.f;
#pragma unroll
        for (int n = 0; n < 2; ++n) {
            int colg = (2 * wave + n) * 16 + lr;
            float bc = b_c1[colg];
            float w2 = W_c2[colg];
            ps0 += silu_f(accZ[m][n][0] + bc) * w2;
            ps1 += silu_f(accZ[m][n][1] + bc) * w2;
            ps2 += silu_f(accZ[m][n][2] + bc) * w2;
            ps3 += silu_f(accZ[m][n][3] + bc) * w2;
        }
        float ps[4] = {ps0, ps1, ps2, ps3};
#pragma unroll
        for (int r = 0; r < 4; ++r) {
            float v = ps[r];
#pragma unroll
            for (int off = 1; off < 16; off <<= 1) v += __shfl_xor(v, off, 64);
            if (lr == 0) atomicAdd(&sS[m * 16 + lq * 4 + r], v);
        }
    }
    __syncthreads();

    // ---- epilogue: coord update + segment-sum atomics ----
    if (tid < 64) {
        int e = tid;
        float inv = tanhf(sS[e]);
        int rI = sRow[e], cI = sCol[e];
        float dx = pos[rI * 3 + 0] - pos[cI * 3 + 0];
        float dy = pos[rI * 3 + 1] - pos[cI * 3 + 1];
        float dz = pos[rI * 3 + 2] - pos[cI * 3 + 2];
        float nrm = sqrtf(dx * dx + dy * dy + dz * dz);
        float f = coord_scale[0] * inv / fmaxf(nrm, 1e-8f);
        atomicAdd(&out[rI * 3 + 0], dx * f);
        atomicAdd(&out[rI * 3 + 1], dy * f);
        atomicAdd(&out[rI * 3 + 2], dz * f);
    }
}

extern "C" void kernel_launch(void* const* d_in, const int* in_sizes, int n_in,
                              void* d_out, int out_size, void* d_ws, size_t ws_size,
                              hipStream_t stream) {
    const float* h          = (const float*)d_in[0];
    const float* pos        = (const float*)d_in[1];
    const float* edge_attr  = (const float*)d_in[2];
    const float* dist       = (const float*)d_in[3];
    const float* time_emb   = (const float*)d_in[4];
    const int*   edge_index = (const int*)d_in[5];
    const float* W_time     = (const float*)d_in[6];
    const float* b_time     = (const float*)d_in[7];
    const float* W_in       = (const float*)d_in[8];
    const float* b_in       = (const float*)d_in[9];
    const float* W_c1       = (const float*)d_in[10];
    const float* b_c1       = (const float*)d_in[11];
    const float* W_c2       = (const float*)d_in[12];
    const float* coord_scale= (const float*)d_in[13];
    float* out = (float*)d_out;

    unsigned short* pWin   = (unsigned short*)d_ws;                       // 704*256*2 = 360448 B
    unsigned short* pWtime = (unsigned short*)((char*)d_ws + 360448);     // 256*512*2 = 262144 B
    unsigned short* pWc1   = (unsigned short*)((char*)d_ws + 622592);     // 256*256*2 = 131072 B

    pack_weights<<<88, 256, 0, stream>>>(W_in,   pWin,   INCH, HID);
    pack_weights<<<64, 256, 0, stream>>>(W_time, pWtime, TDIM, 2 * HID);
    pack_weights<<<32, 256, 0, stream>>>(W_c1,   pWc1,   HID,  HID);
    init_out<<<(3 * NN + 255) / 256, 256, 0, stream>>>(pos, out, 3 * NN);

    edge_kernel<<<NE / 64, 512, 0, stream>>>(
        h, pos, edge_attr, dist, time_emb, edge_index,
        b_time, b_in, b_c1, W_c2, coord_scale,
        pWtime, pWin, pWc1, out);
}